// Round 3
// baseline (3710.323 us; speedup 1.0000x reference)
//
#include <hip/hip_runtime.h>

#define RSQRT8    0.35355339059327373f
#define RSQRT128  0.08838834764831845f
#define RSQRT192  0.07216878364870323f
#define RSQRT64   0.125f
#define INV_SQRT3 0.57735026918962576f
#define SEG_NORM  0.25f       /* 1/sqrt(16) */
#define C_HALF    0.70710678118654752f
#define SQ23      0.81649658092772603f
#define SQ13      0.57735026918962576f

// LDS row strides (elements). Chosen so stride-in-dwords % 32 == 6 (2-way bank
// aliasing = free) while keeping 8-byte alignment for uint2/float2 staging.
#define XB 204   // bf16 tile: [0:128] lat/lat2, [128:192] sscal   (408 B/row)
#define FB 140   // bf16 tile: feat -> h                           (280 B/row)
#define GB 134   // f32  tile: env gather                          (536 B/row)
#define XA 133   // f32  tile (phase A), odd stride -> conflict-free scalar

__device__ __forceinline__ float bf2f(unsigned short b) {
    return __uint_as_float(((unsigned int)b) << 16);
}
__device__ __forceinline__ unsigned short f2bf(float f) {
    unsigned int u = __float_as_uint(f);
    u += 0x7FFFu + ((u >> 16) & 1u);           // round-to-nearest-even
    return (unsigned short)(u >> 16);
}
__device__ __forceinline__ float silu_f(float x) { return x / (1.0f + __expf(-x)); }

// GEMV with per-lane activation row (LDS) and wave-uniform weight loads.
// cb must be wave-uniform (derived from readfirstlane) so W addressing
// scalarizes to s_load; x is one ds_read per k for 32 (NC) FMAs.
template<int K, int N, int NC>
__device__ __forceinline__ void gemv_bf(const unsigned short* xrow,
                                        const float* __restrict__ W,
                                        int cb, float* acc)
{
#pragma unroll
    for (int c = 0; c < NC; ++c) acc[c] = 0.f;
    for (int k = 0; k < K; ++k) {
        float x = bf2f(xrow[k]);
        const float* wr = W + (size_t)k * N + cb;
#pragma unroll
        for (int c = 0; c < NC; ++c) acc[c] = fmaf(x, wr[c], acc[c]);
    }
}

template<int K, int N, int NC>
__device__ __forceinline__ void gemv_f32(const float* xrow,
                                         const float* __restrict__ W,
                                         int cb, float* acc)
{
#pragma unroll
    for (int c = 0; c < NC; ++c) acc[c] = 0.f;
    for (int k = 0; k < K; ++k) {
        float x = xrow[k];
        const float* wr = W + (size_t)k * N + cb;
#pragma unroll
        for (int c = 0; c < NC; ++c) acc[c] = fmaf(x, wr[c], acc[c]);
    }
}

// ---------------------------------------------------------------------------
// Phase A: lat = mlp2(inv); w0 = lat@Wenv0; env_weight -> featbuf + env0 atomics
// block = 256 thr = 4 waves; 64 edges/block; thread = (edge=lane, 32 cols/wave)
// ---------------------------------------------------------------------------
__global__ __launch_bounds__(256, 2) void phaseA(
    const int* __restrict__ eidx, const float* __restrict__ attr,
    const float* __restrict__ inv,
    const float* __restrict__ W2b0, const float* __restrict__ W2b1,
    const float* __restrict__ Wenv0,
    unsigned short* __restrict__ latbuf, unsigned short* __restrict__ featbuf,
    float* __restrict__ env0, int E)
{
    __shared__ float sx[64][9];
    __shared__ float xt[64][XA];
    const int tid  = threadIdx.x;
    const int lane = tid & 63;
    const int wq   = __builtin_amdgcn_readfirstlane(tid >> 6);
    const int e0   = blockIdx.x * 64;
    const int e    = e0 + lane;
    const bool val = (e < E);
    const int ecl  = min(e, E - 1);
    const int cb   = wq * 32;

    for (int i = tid; i < 64 * 8; i += 256) {
        int r = i >> 3, k = i & 7;
        sx[r][k] = inv[(size_t)min(e0 + r, E - 1) * 8 + k];
    }
    __syncthreads();

    float acc[32];
    // GEMV1: inv(8) @ W2b0 -> silu -> h
#pragma unroll
    for (int c = 0; c < 32; ++c) acc[c] = 0.f;
#pragma unroll
    for (int k = 0; k < 8; ++k) {
        float x = sx[lane][k];
        const float* wr = W2b0 + k * 128 + cb;
#pragma unroll
        for (int c = 0; c < 32; ++c) acc[c] = fmaf(x, wr[c], acc[c]);
    }
#pragma unroll
    for (int c = 0; c < 32; ++c) xt[lane][cb + c] = silu_f(acc[c] * RSQRT8);
    __syncthreads();

    // GEMV2: h(128) @ W2b1 -> lat
    gemv_f32<128, 128, 32>(&xt[lane][0], W2b1, cb, acc);
    float latv[32];
#pragma unroll
    for (int c = 0; c < 32; ++c) latv[c] = acc[c] * RSQRT128;
    if (val) {
        unsigned short* dst = latbuf + (size_t)e * 128 + cb;
#pragma unroll
        for (int c = 0; c < 32; ++c) dst[c] = f2bf(latv[c]);
    }
    __syncthreads();               // all h reads done
#pragma unroll
    for (int c = 0; c < 32; ++c) xt[lane][cb + c] = latv[c];
    __syncthreads();

    // GEMV3: lat(128) @ Wenv0 -> w0
    gemv_f32<128, 128, 32>(&xt[lane][0], Wenv0, cb, acc);
    float w0[32];
#pragma unroll
    for (int c = 0; c < 32; ++c) w0[c] = acc[c] * RSQRT128;

    // env_weight: w0 cols 0..63 -> features (waves 0,1); 64..127 -> env (waves 2,3)
    const float4 av = ((const float4*)attr)[ecl];
    if (wq < 2) {
        if (val) {
            unsigned short* dst = featbuf + (size_t)e * 128 + wq * 64;
#pragma unroll
            for (int mi = 0; mi < 16; ++mi) {
                float s = w0[2 * mi], v = w0[2 * mi + 1];
                dst[4 * mi + 0] = f2bf(s * av.x);
                dst[4 * mi + 1] = f2bf(v * av.y);
                dst[4 * mi + 2] = f2bf(v * av.z);
                dst[4 * mi + 3] = f2bf(v * av.w);
            }
        }
    } else {
        if (val) {
            const int node = eidx[e];
            float* dst = env0 + (size_t)node * 128 + (wq - 2) * 64;
#pragma unroll
            for (int mi = 0; mi < 16; ++mi) {
                float s = w0[2 * mi], v = w0[2 * mi + 1];
                atomicAdd(&dst[4 * mi + 0], s * av.x);
                atomicAdd(&dst[4 * mi + 1], v * av.y);
                atomicAdd(&dst[4 * mi + 2], v * av.z);
                atomicAdd(&dst[4 * mi + 3], v * av.w);
            }
        }
    }
}

// ---------------------------------------------------------------------------
// Phase B: tensor products + Ws0/Wv0 mix -> feat2; new_lat MLP; lat2; Wenv1 scatter
// ---------------------------------------------------------------------------
__global__ __launch_bounds__(256, 2) void phaseB(
    const int* __restrict__ eidx, const float* __restrict__ attr,
    const float* __restrict__ env0,
    const float* __restrict__ Ws0, const float* __restrict__ Wv0,
    const float* __restrict__ Wlat1_0, const float* __restrict__ Wlat1_1,
    const float* __restrict__ Wenv1,
    unsigned short* __restrict__ latbuf, unsigned short* __restrict__ featbuf,
    float* __restrict__ env1, int E)
{
    __shared__ unsigned short xt[64][XB];
    __shared__ unsigned short ft[64][FB];
    __shared__ float          gt[64][GB];
    const int tid  = threadIdx.x;
    const int lane = tid & 63;
    const int wq   = __builtin_amdgcn_readfirstlane(tid >> 6);
    const int e0   = blockIdx.x * 64;
    const int e    = e0 + lane;
    const bool val = (e < E);
    const int ecl  = min(e, E - 1);
    const int cb   = wq * 32;

    {   // stage: lat -> xt[:,0:128], feat -> ft, env0 gather -> gt
        const int r = tid & 63, q = tid >> 6;
        const int er = min(e0 + r, E - 1);
        const uint2* srcl = (const uint2*)(latbuf + (size_t)er * 128 + q * 32);
        uint2* dstx = (uint2*)&xt[r][q * 32];
#pragma unroll
        for (int i = 0; i < 8; ++i) dstx[i] = srcl[i];
        const uint2* srcf = (const uint2*)(featbuf + (size_t)er * 128 + q * 32);
        uint2* dstf = (uint2*)&ft[r][q * 32];
#pragma unroll
        for (int i = 0; i < 8; ++i) dstf[i] = srcf[i];
        const int node = eidx[er];
        const float2* srcg = (const float2*)(env0 + (size_t)node * 128 + q * 32);
        float2* dstg = (float2*)&gt[r][q * 32];
#pragma unroll
        for (int i = 0; i < 16; ++i) {
            float2 v = srcg[i]; v.x *= SEG_NORM; v.y *= SEG_NORM; dstg[i] = v;
        }
    }
    __syncthreads();

    {   // sscal interleaved -> xt[:,128:192]: [2m]=ss, [2m+1]=vv
        const int r = tid & 63, q = tid >> 6;
#pragma unroll
        for (int mi = 0; mi < 8; ++mi) {
            int m = q * 8 + mi;
            float f0 = bf2f(ft[r][4 * m]),     g0 = gt[r][4 * m];
            float f1 = bf2f(ft[r][4 * m + 1]), g1 = gt[r][4 * m + 1];
            float f2 = bf2f(ft[r][4 * m + 2]), g2 = gt[r][4 * m + 2];
            float f3 = bf2f(ft[r][4 * m + 3]), g3 = gt[r][4 * m + 3];
            xt[r][128 + 2 * m]     = f2bf(f0 * g0);
            xt[r][128 + 2 * m + 1] = f2bf((f1 * g1 + f2 * g2 + f3 * g3) * INV_SQRT3);
        }
    }
    __syncthreads();

    {   // feat2 mix: thread covers chs cb..cb+31 -> m = 8wq..8wq+7, all j
        const int mb = wq * 8;
        float fa[32];
#pragma unroll
        for (int c = 0; c < 32; ++c) fa[c] = 0.f;
        for (int c = 0; c < 32; ++c) {          // s-path: s_in @ Ws0
            float s0 = bf2f(xt[lane][128 + 2 * c]);       // out_ss[c]
            float s1 = bf2f(xt[lane][128 + 2 * c + 1]);   // out_vv[c]
            const float* w0r = Ws0 + c * 32 + mb;
            const float* w1r = Ws0 + (32 + c) * 32 + mb;
#pragma unroll
            for (int mi = 0; mi < 8; ++mi)
                fa[4 * mi] = fmaf(s0, w0r[mi], fmaf(s1, w1r[mi], fa[4 * mi]));
        }
        for (int c = 0; c < 32; ++c) {          // v-path: [sv|vs] @ Wv0
            float x0 = bf2f(ft[lane][4 * c]);
            float y0 = gt[lane][4 * c];
            float sv1 = x0 * gt[lane][4 * c + 1];
            float sv2 = x0 * gt[lane][4 * c + 2];
            float sv3 = x0 * gt[lane][4 * c + 3];
            float vs1 = bf2f(ft[lane][4 * c + 1]) * y0;
            float vs2 = bf2f(ft[lane][4 * c + 2]) * y0;
            float vs3 = bf2f(ft[lane][4 * c + 3]) * y0;
            const float* wa = Wv0 + c * 32 + mb;
            const float* wb = Wv0 + (32 + c) * 32 + mb;
#pragma unroll
            for (int mi = 0; mi < 8; ++mi) {
                float WA = wa[mi], WB = wb[mi];
                fa[4 * mi + 1] = fmaf(sv1, WA, fmaf(vs1, WB, fa[4 * mi + 1]));
                fa[4 * mi + 2] = fmaf(sv2, WA, fmaf(vs2, WB, fa[4 * mi + 2]));
                fa[4 * mi + 3] = fmaf(sv3, WA, fmaf(vs3, WB, fa[4 * mi + 3]));
            }
        }
        if (val) {
            unsigned short* dst = featbuf + (size_t)e * 128 + cb;
#pragma unroll
            for (int mi = 0; mi < 8; ++mi) {
                dst[4 * mi + 0] = f2bf(fa[4 * mi + 0] * RSQRT64);
                dst[4 * mi + 1] = f2bf(fa[4 * mi + 1] * (RSQRT64 * INV_SQRT3));
                dst[4 * mi + 2] = f2bf(fa[4 * mi + 2] * (RSQRT64 * INV_SQRT3));
                dst[4 * mi + 3] = f2bf(fa[4 * mi + 3] * (RSQRT64 * INV_SQRT3));
            }
        }
    }

    // GEMV4: [lat|sscal](192) @ Wlat1_0 -> silu -> h
    float acc[32];
    gemv_bf<192, 128, 32>(&xt[lane][0], Wlat1_0, cb, acc);
    float h[32];
#pragma unroll
    for (int c = 0; c < 32; ++c) h[c] = silu_f(acc[c] * RSQRT192);
    __syncthreads();               // ft (mix) + xt (gemv4) reads done
#pragma unroll
    for (int c = 0; c < 32; ++c) ft[lane][cb + c] = f2bf(h[c]);
    __syncthreads();

    // GEMV5: h(128) @ Wlat1_1 -> new_lat; lat2 = c*(lat+new_lat)
    gemv_bf<128, 128, 32>(&ft[lane][0], Wlat1_1, cb, acc);
    float l2[32];
#pragma unroll
    for (int c = 0; c < 32; ++c)
        l2[c] = C_HALF * (bf2f(xt[lane][cb + c]) + acc[c] * RSQRT128);
    if (val) {
        unsigned short* dst = latbuf + (size_t)e * 128 + cb;
#pragma unroll
        for (int c = 0; c < 32; ++c) dst[c] = f2bf(l2[c]);
    }
    __syncthreads();               // all lat reads of xt done
#pragma unroll
    for (int c = 0; c < 32; ++c) xt[lane][cb + c] = f2bf(l2[c]);
    __syncthreads();

    // GEMV6: lat2(128) @ Wenv1(128x64) -> w1; env_weight scatter
    float acc6[16];
    gemv_bf<128, 64, 16>(&xt[lane][0], Wenv1, wq * 16, acc6);
    const float4 av = ((const float4*)attr)[ecl];
    if (val) {
        const int node = eidx[e];
        float* dst = env1 + (size_t)node * 128 + wq * 32;
#pragma unroll
        for (int mi = 0; mi < 8; ++mi) {
            float s = acc6[2 * mi] * RSQRT128, v = acc6[2 * mi + 1] * RSQRT128;
            atomicAdd(&dst[4 * mi + 0], s * av.x);
            atomicAdd(&dst[4 * mi + 1], v * av.y);
            atomicAdd(&dst[4 * mi + 2], v * av.z);
            atomicAdd(&dst[4 * mi + 3], v * av.w);
        }
    }
}

// ---------------------------------------------------------------------------
// Phase C: gather env1, scalars1, final MLP, output mix (fp32 out).
// ---------------------------------------------------------------------------
__global__ __launch_bounds__(256, 2) void phaseC(
    const int* __restrict__ eidx, const float* __restrict__ env1,
    const float* __restrict__ Wfin0, const float* __restrict__ Wfin1,
    const unsigned short* __restrict__ latbuf, const unsigned short* __restrict__ featbuf,
    float* __restrict__ outp, int E)
{
    __shared__ unsigned short xt[64][XB];
    __shared__ unsigned short ft[64][FB];
    __shared__ float          gt[64][GB];
    const int tid  = threadIdx.x;
    const int lane = tid & 63;
    const int wq   = __builtin_amdgcn_readfirstlane(tid >> 6);
    const int e0   = blockIdx.x * 64;
    const int e    = e0 + lane;
    const bool val = (e < E);
    const int cb   = wq * 32;

    {   // stage lat2 -> xt, feat2 -> ft, env1 gather -> gt
        const int r = tid & 63, q = tid >> 6;
        const int er = min(e0 + r, E - 1);
        const uint2* srcl = (const uint2*)(latbuf + (size_t)er * 128 + q * 32);
        uint2* dstx = (uint2*)&xt[r][q * 32];
#pragma unroll
        for (int i = 0; i < 8; ++i) dstx[i] = srcl[i];
        const uint2* srcf = (const uint2*)(featbuf + (size_t)er * 128 + q * 32);
        uint2* dstf = (uint2*)&ft[r][q * 32];
#pragma unroll
        for (int i = 0; i < 8; ++i) dstf[i] = srcf[i];
        const int node = eidx[er];
        const float2* srcg = (const float2*)(env1 + (size_t)node * 128 + q * 32);
        float2* dstg = (float2*)&gt[r][q * 32];
#pragma unroll
        for (int i = 0; i < 16; ++i) {
            float2 v = srcg[i]; v.x *= SEG_NORM; v.y *= SEG_NORM; dstg[i] = v;
        }
    }
    __syncthreads();

    {   // scalars1 -> xt[:,128:192]
        const int r = tid & 63, q = tid >> 6;
#pragma unroll
        for (int mi = 0; mi < 8; ++mi) {
            int m = q * 8 + mi;
            float f0 = bf2f(ft[r][4 * m]),     g0 = gt[r][4 * m];
            float f1 = bf2f(ft[r][4 * m + 1]), g1 = gt[r][4 * m + 1];
            float f2 = bf2f(ft[r][4 * m + 2]), g2 = gt[r][4 * m + 2];
            float f3 = bf2f(ft[r][4 * m + 3]), g3 = gt[r][4 * m + 3];
            xt[r][128 + 2 * m]     = f2bf(f0 * g0);
            xt[r][128 + 2 * m + 1] = f2bf((f1 * g1 + f2 * g2 + f3 * g3) * INV_SQRT3);
        }
    }
    __syncthreads();

    // GEMV7: [lat2|scalars1](192) @ Wfin0 -> silu -> h
    float acc[32];
    gemv_bf<192, 128, 32>(&xt[lane][0], Wfin0, cb, acc);
    float h[32];
#pragma unroll
    for (int c = 0; c < 32; ++c) h[c] = silu_f(acc[c] * RSQRT192);
    __syncthreads();
#pragma unroll
    for (int c = 0; c < 32; ++c) ft[lane][cb + c] = f2bf(h[c]);
    __syncthreads();

    // GEMV8: h(128) @ Wfin1 -> new_lat; out = sqrt(2/3)*lat2 + sqrt(1/3)*new_lat
    gemv_bf<128, 128, 32>(&ft[lane][0], Wfin1, cb, acc);
    if (val) {
        float* dst = outp + (size_t)e * 128 + cb;
#pragma unroll
        for (int c = 0; c < 32; ++c)
            dst[c] = SQ23 * bf2f(xt[lane][cb + c]) + SQ13 * (acc[c] * RSQRT128);
    }
}

extern "C" void kernel_launch(void* const* d_in, const int* in_sizes, int n_in,
                              void* d_out, int out_size, void* d_ws, size_t ws_size,
                              hipStream_t stream)
{
    const int E  = in_sizes[0] / 2;   // edge_index is (2, E)
    const int NN = 12500;             // num_nodes (fixed by problem setup)

    const int*   eidx    = (const int*)d_in[0];
    const float* attr    = (const float*)d_in[1];
    const float* inv     = (const float*)d_in[2];
    const float* W2b0    = (const float*)d_in[3];
    const float* W2b1    = (const float*)d_in[4];
    const float* Wenv0   = (const float*)d_in[5];
    const float* Wlat1_0 = (const float*)d_in[6];
    const float* Wlat1_1 = (const float*)d_in[7];
    const float* Wenv1   = (const float*)d_in[8];
    const float* Ws0     = (const float*)d_in[9];
    const float* Wv0     = (const float*)d_in[10];
    const float* Wfin0   = (const float*)d_in[11];
    const float* Wfin1   = (const float*)d_in[12];
    float* outp = (float*)d_out;

    // ws carve: lat (E*128 bf16) | feat (E*128 bf16) | env0, env1 (NN*128 f32)
    unsigned short* latbuf  = (unsigned short*)d_ws;
    unsigned short* featbuf = latbuf + (size_t)E * 128;
    float* env0 = (float*)(featbuf + (size_t)E * 128);
    float* env1 = env0 + (size_t)NN * 128;

    hipMemsetAsync(env0, 0, (size_t)NN * 128 * 2 * sizeof(float), stream);

    const int nb = (E + 63) / 64;
    phaseA<<<nb, 256, 0, stream>>>(eidx, attr, inv, W2b0, W2b1, Wenv0,
                                   latbuf, featbuf, env0, E);
    phaseB<<<nb, 256, 0, stream>>>(eidx, attr, env0, Ws0, Wv0,
                                   Wlat1_0, Wlat1_1, Wenv1,
                                   latbuf, featbuf, env1, E);
    phaseC<<<nb, 256, 0, stream>>>(eidx, env1, Wfin0, Wfin1,
                                   latbuf, featbuf, outp, E);
}

// Round 4
// 1247.257 us; speedup vs baseline: 2.9748x; 2.9748x over previous
//
#include <hip/hip_runtime.h>

typedef __attribute__((ext_vector_type(8))) short bf8_t;   // 8 x bf16 (4 VGPRs)
typedef __attribute__((ext_vector_type(4))) float f4_t;    // 4 x fp32 acc

#define MFMA16 __builtin_amdgcn_mfma_f32_16x16x32_bf16

#define RSQRT8    0.35355339059327373f
#define RSQRT128  0.08838834764831845f
#define RSQRT192  0.07216878364870323f
#define RSQRT64   0.125f
#define INV_SQRT3 0.57735026918962576f
#define SEG_NORM  0.25f       /* 1/sqrt(16) */
#define C_HALF    0.70710678118654752f
#define SQ23      0.81649658092772603f
#define SQ13      0.57735026918962576f

__device__ __forceinline__ float bf2f(unsigned short b) {
    return __uint_as_float(((unsigned int)b) << 16);
}
__device__ __forceinline__ unsigned short f2bf(float f) {
    unsigned int u = __float_as_uint(f);
    u += 0x7FFFu + ((u >> 16) & 1u);           // round-to-nearest-even
    return (unsigned short)(u >> 16);
}
__device__ __forceinline__ float silu_f(float x) { return x / (1.0f + __expf(-x)); }

// One wave computes a 16-row strip of C = A @ (Whi+Wlo) using 16x16x32 bf16 MFMA.
// A: LDS, row-major, stride `as` shorts (as*2 must be 16B-multiple).
// Wh/Wl: global, transposed [N][Kp] bf16 (hi/lo split), Kp multiple of 32.
// acc[NTILES]: fp32 accumulators (col tile n covers cols n*16..n*16+15).
template<int KSTEPS, int NTILES>
__device__ __forceinline__ void gemm_strip(
    const unsigned short* A, int as,
    const unsigned short* __restrict__ Wh, const unsigned short* __restrict__ Wl,
    int Kp, int lane, f4_t* acc)
{
    const int r = lane & 15, q = lane >> 4;
    const unsigned short* arow = A + r * as + q * 8;
    const unsigned short* wh = Wh + (size_t)r * Kp + q * 8;
    const unsigned short* wl = Wl + (size_t)r * Kp + q * 8;
#pragma unroll 2
    for (int ks = 0; ks < KSTEPS; ++ks) {
        bf8_t a = *(const bf8_t*)(arow + ks * 32);
#pragma unroll
        for (int n = 0; n < NTILES; ++n) {
            bf8_t bh = *(const bf8_t*)(wh + n * 16 * Kp + ks * 32);
            bf8_t bl = *(const bf8_t*)(wl + n * 16 * Kp + ks * 32);
            acc[n] = MFMA16(a, bl, acc[n], 0, 0, 0);
            acc[n] = MFMA16(a, bh, acc[n], 0, 0, 0);
        }
    }
}

// ---------------------------------------------------------------------------
// Weight prep: fp32 [K][N] -> transposed bf16 hi/lo [N][Kp], zero-padded,
// optional row-permute for the scalars block (interleaved -> concat order).
// ---------------------------------------------------------------------------
__global__ void prep_w(const float* __restrict__ src,
                       unsigned short* __restrict__ hi, unsigned short* __restrict__ lo,
                       int K, int N, int Kp, int perm)
{
    int i = blockIdx.x * 256 + threadIdx.x;
    if (i >= N * Kp) return;
    int n = i / Kp, k = i - n * Kp;
    int ks = k;
    if (perm && k >= 128) ks = (k < 160) ? (128 + 2 * (k - 128)) : (129 + 2 * (k - 160));
    float wv = (ks < K) ? src[(size_t)ks * N + n] : 0.f;
    unsigned short h = f2bf(wv);
    hi[i] = h;
    lo[i] = f2bf(wv - bf2f(h));
}

// ---------------------------------------------------------------------------
// Phase A: lat = mlp2(inv); w0 = lat@Wenv0; env_weight -> featbuf + env0 atomics
// ---------------------------------------------------------------------------
__global__ __launch_bounds__(256) void phaseA(
    const int* __restrict__ eidx, const float* __restrict__ attr,
    const float* __restrict__ inv,
    const unsigned short* __restrict__ Wh2b0, const unsigned short* __restrict__ Wl2b0,
    const unsigned short* __restrict__ Wh2b1, const unsigned short* __restrict__ Wl2b1,
    const unsigned short* __restrict__ Whenv0, const unsigned short* __restrict__ Wlenv0,
    unsigned short* __restrict__ latbuf, unsigned short* __restrict__ featbuf,
    float* __restrict__ env0, int E)
{
    __shared__ __align__(16) unsigned short Xi[64][32];
    __shared__ __align__(16) unsigned short Hs[64][136];
    __shared__ __align__(16) unsigned short Ls[64][136];
    __shared__ __align__(16) float W0s[64][132];
    __shared__ float sattr[64][4];
    __shared__ int snode[64];

    const int tid = threadIdx.x;
    const int lane = tid & 63;
    const int w = tid >> 6;
    const int e0 = blockIdx.x * 64;
    const int E1 = E - 1;
    const int r = lane & 15, q = lane >> 4;

    for (int i = tid; i < 64 * 32; i += 256) {
        int t = i >> 5, c = i & 31;
        unsigned short v = 0;
        if (c < 8) v = f2bf(inv[(size_t)min(e0 + t, E1) * 8 + c]);
        Xi[t][c] = v;                                  // zero-padded K=8 -> 32
    }
    { int t = tid >> 2, c = tid & 3; sattr[t][c] = attr[(size_t)min(e0 + t, E1) * 4 + c]; }
    if (tid < 64) snode[tid] = eidx[min(e0 + tid, E1)];
    __syncthreads();

    const f4_t z = {0.f, 0.f, 0.f, 0.f};
    f4_t acc[8];

    // GEMM1: inv(8->32) @ W2b0 -> silu -> Hs
#pragma unroll
    for (int n = 0; n < 8; ++n) acc[n] = z;
    gemm_strip<1, 8>(&Xi[w * 16][0], 32, Wh2b0, Wl2b0, 32, lane, acc);
#pragma unroll
    for (int n = 0; n < 8; ++n)
#pragma unroll
        for (int jj = 0; jj < 4; ++jj)
            Hs[w * 16 + q * 4 + jj][n * 16 + r] = f2bf(silu_f(acc[n][jj] * RSQRT8));
    __syncthreads();

    // GEMM2: h(128) @ W2b1 -> lat -> Ls + latbuf
#pragma unroll
    for (int n = 0; n < 8; ++n) acc[n] = z;
    gemm_strip<4, 8>(&Hs[w * 16][0], 136, Wh2b1, Wl2b1, 128, lane, acc);
#pragma unroll
    for (int n = 0; n < 8; ++n)
#pragma unroll
        for (int jj = 0; jj < 4; ++jj) {
            int row = w * 16 + q * 4 + jj, cc = n * 16 + r;
            unsigned short b = f2bf(acc[n][jj] * RSQRT128);
            Ls[row][cc] = b;
            int e = e0 + row;
            if (e < E) latbuf[(size_t)e * 128 + cc] = b;
        }
    __syncthreads();

    // GEMM3: lat(128) @ Wenv0 -> w0 (fp32 LDS)
#pragma unroll
    for (int n = 0; n < 8; ++n) acc[n] = z;
    gemm_strip<4, 8>(&Ls[w * 16][0], 136, Whenv0, Wlenv0, 128, lane, acc);
#pragma unroll
    for (int n = 0; n < 8; ++n)
#pragma unroll
        for (int jj = 0; jj < 4; ++jj)
            W0s[w * 16 + q * 4 + jj][n * 16 + r] = acc[n][jj] * RSQRT128;
    __syncthreads();

    // env_weight: coalesced per-edge (128 consecutive channels) stores/atomics
    {
        const int ch = tid & 127, half = tid >> 7;
        const int mm = ch >> 2, jj = ch & 3;
        const int widx = (jj == 0) ? 2 * mm : 2 * mm + 1;
        if (half == 0) {
            for (int t = 0; t < 64; ++t) {
                int e = e0 + t;
                if (e < E) featbuf[(size_t)e * 128 + ch] = f2bf(W0s[t][widx] * sattr[t][jj]);
            }
        } else {
            for (int t = 0; t < 64; ++t) {
                int e = e0 + t;
                if (e < E) atomicAdd(&env0[(size_t)snode[t] * 128 + ch],
                                     W0s[t][64 + widx] * sattr[t][jj]);
            }
        }
    }
}

// ---------------------------------------------------------------------------
// Phase B: tensor products + mix -> feat2; new_lat MLP; lat2; Wenv1 scatter
// ---------------------------------------------------------------------------
__global__ __launch_bounds__(256) void phaseB(
    const int* __restrict__ eidx, const float* __restrict__ attr,
    const float* __restrict__ env0,
    const unsigned short* __restrict__ Whs0, const unsigned short* __restrict__ Wls0,
    const unsigned short* __restrict__ Whv0, const unsigned short* __restrict__ Wlv0,
    const unsigned short* __restrict__ Whl10, const unsigned short* __restrict__ Wll10,
    const unsigned short* __restrict__ Whl11, const unsigned short* __restrict__ Wll11,
    const unsigned short* __restrict__ Whe1, const unsigned short* __restrict__ Wle1,
    unsigned short* __restrict__ latbuf, unsigned short* __restrict__ featbuf,
    float* __restrict__ env1, int E)
{
    __shared__ __align__(16) char sm[89344];
    unsigned short (*X4)[200] = (unsigned short (*)[200])sm;              // lat|sscal
    unsigned short (*Ft)[136] = (unsigned short (*)[136])(sm + 25600);    // feat -> feat2
    unsigned short (*Gt)[136] = (unsigned short (*)[136])(sm + 43008);    // env gather
    unsigned short (*Xv0)[72] = (unsigned short (*)[72])(sm + 60416);
    unsigned short (*Xv1)[72] = (unsigned short (*)[72])(sm + 60416 + 9216);
    unsigned short (*Xv2)[72] = (unsigned short (*)[72])(sm + 60416 + 18432);
    unsigned short (*Hs)[136] = (unsigned short (*)[136])(sm + 60416);    // overlays Xv (dead)
    float (*W1s)[68]          = (float (*)[68])(sm + 60416);              // overlays Hs (dead)
    float (*sattr)[4]         = (float (*)[4])(sm + 88064);
    int* snode                = (int*)(sm + 89088);

    const int tid = threadIdx.x;
    const int lane = tid & 63;
    const int w = tid >> 6;
    const int e0 = blockIdx.x * 64;
    const int E1 = E - 1;
    const int r = lane & 15, q = lane >> 4;

    { int t = tid >> 2, c = tid & 3; sattr[t][c] = attr[(size_t)min(e0 + t, E1) * 4 + c]; }
    if (tid < 64) snode[tid] = eidx[min(e0 + tid, E1)];
    __syncthreads();

    // stage: lat -> X4[:,0:128], feat -> Ft, env0 gather -> Gt (bf16 * SEG_NORM)
    for (int i = tid; i < 64 * 64; i += 256) {
        int t = i >> 6, dc = i & 63;
        int e = min(e0 + t, E1);
        ((unsigned int*)&X4[t][0])[dc] = ((const unsigned int*)(latbuf + (size_t)e * 128))[dc];
        ((unsigned int*)&Ft[t][0])[dc] = ((const unsigned int*)(featbuf + (size_t)e * 128))[dc];
    }
    for (int i = tid; i < 64 * 128; i += 256) {
        int t = i >> 7, c = i & 127;
        Gt[t][c] = f2bf(env0[(size_t)snode[t] * 128 + c] * SEG_NORM);
    }
    __syncthreads();

    // sscal (concat order, W permuted) + v-operand tiles
    for (int i = tid; i < 64 * 32; i += 256) {
        int t = i >> 5, mm = i & 31;
        float f0 = bf2f(Ft[t][4 * mm]),     g0 = bf2f(Gt[t][4 * mm]);
        float f1 = bf2f(Ft[t][4 * mm + 1]), g1 = bf2f(Gt[t][4 * mm + 1]);
        float f2 = bf2f(Ft[t][4 * mm + 2]), g2 = bf2f(Gt[t][4 * mm + 2]);
        float f3 = bf2f(Ft[t][4 * mm + 3]), g3 = bf2f(Gt[t][4 * mm + 3]);
        X4[t][128 + mm] = f2bf(f0 * g0);                                       // ss
        X4[t][160 + mm] = f2bf((f1 * g1 + f2 * g2 + f3 * g3) * INV_SQRT3);     // vv
        Xv0[t][mm] = f2bf(f0 * g1);  Xv0[t][32 + mm] = f2bf(f1 * g0);          // sv|vs
        Xv1[t][mm] = f2bf(f0 * g2);  Xv1[t][32 + mm] = f2bf(f2 * g0);
        Xv2[t][mm] = f2bf(f0 * g3);  Xv2[t][32 + mm] = f2bf(f3 * g0);
    }
    __syncthreads();

    const f4_t z = {0.f, 0.f, 0.f, 0.f};
    // mix GEMMs: K=64, N=32
    f4_t aS[2] = {z, z}, aV0[2] = {z, z}, aV1[2] = {z, z}, aV2[2] = {z, z};
    gemm_strip<2, 2>(&X4[w * 16][128], 200, Whs0, Wls0, 64, lane, aS);
    gemm_strip<2, 2>(&Xv0[w * 16][0],   72, Whv0, Wlv0, 64, lane, aV0);
    gemm_strip<2, 2>(&Xv1[w * 16][0],   72, Whv0, Wlv0, 64, lane, aV1);
    gemm_strip<2, 2>(&Xv2[w * 16][0],   72, Whv0, Wlv0, 64, lane, aV2);
#pragma unroll
    for (int n = 0; n < 2; ++n)
#pragma unroll
        for (int jj = 0; jj < 4; ++jj) {
            int row = w * 16 + q * 4 + jj, cc = n * 16 + r;
            Ft[row][4 * cc + 0] = f2bf(aS[n][jj]  * RSQRT64);
            Ft[row][4 * cc + 1] = f2bf(aV0[n][jj] * (RSQRT64 * INV_SQRT3));
            Ft[row][4 * cc + 2] = f2bf(aV1[n][jj] * (RSQRT64 * INV_SQRT3));
            Ft[row][4 * cc + 3] = f2bf(aV2[n][jj] * (RSQRT64 * INV_SQRT3));
        }
    __syncthreads();

    // feat2 -> featbuf (coalesced) ; GEMM4: [lat|sscal](192) @ Wlat1_0 -> silu -> Hs
    for (int i = tid; i < 64 * 64; i += 256) {
        int t = i >> 6, dc = i & 63;
        int e = e0 + t;
        if (e < E) ((unsigned int*)(featbuf + (size_t)e * 128))[dc] = ((unsigned int*)&Ft[t][0])[dc];
    }
    f4_t acc[8];
#pragma unroll
    for (int n = 0; n < 8; ++n) acc[n] = z;
    gemm_strip<6, 8>(&X4[w * 16][0], 200, Whl10, Wll10, 192, lane, acc);
#pragma unroll
    for (int n = 0; n < 8; ++n)
#pragma unroll
        for (int jj = 0; jj < 4; ++jj)
            Hs[w * 16 + q * 4 + jj][n * 16 + r] = f2bf(silu_f(acc[n][jj] * RSQRT192));
    __syncthreads();

    // GEMM5: h @ Wlat1_1 -> new_lat; lat2 = C*(lat+new_lat) in-place in X4
#pragma unroll
    for (int n = 0; n < 8; ++n) acc[n] = z;
    gemm_strip<4, 8>(&Hs[w * 16][0], 136, Whl11, Wll11, 128, lane, acc);
#pragma unroll
    for (int n = 0; n < 8; ++n)
#pragma unroll
        for (int jj = 0; jj < 4; ++jj) {
            int row = w * 16 + q * 4 + jj, cc = n * 16 + r;
            float l2 = C_HALF * (bf2f(X4[row][cc]) + acc[n][jj] * RSQRT128);
            X4[row][cc] = f2bf(l2);
        }
    __syncthreads();

    // lat2 -> latbuf (coalesced); GEMM6: lat2 @ Wenv1(128x64) -> w1 (fp32 LDS)
    for (int i = tid; i < 64 * 64; i += 256) {
        int t = i >> 6, dc = i & 63;
        int e = e0 + t;
        if (e < E) ((unsigned int*)(latbuf + (size_t)e * 128))[dc] = ((unsigned int*)&X4[t][0])[dc];
    }
    f4_t a6[4] = {z, z, z, z};
    gemm_strip<4, 4>(&X4[w * 16][0], 200, Whe1, Wle1, 128, lane, a6);
#pragma unroll
    for (int n = 0; n < 4; ++n)
#pragma unroll
        for (int jj = 0; jj < 4; ++jj)
            W1s[w * 16 + q * 4 + jj][n * 16 + r] = a6[n][jj] * RSQRT128;
    __syncthreads();

    // env1 scatter: 2 edges per iter, 128 consecutive channels each (coalesced)
    {
        const int ch = tid & 127, half = tid >> 7;
        const int mm = ch >> 2, jj = ch & 3;
        const int widx = (jj == 0) ? 2 * mm : 2 * mm + 1;
        for (int t = half; t < 64; t += 2) {
            int e = e0 + t;
            if (e < E) atomicAdd(&env1[(size_t)snode[t] * 128 + ch],
                                 W1s[t][widx] * sattr[t][jj]);
        }
    }
}

// ---------------------------------------------------------------------------
// Phase C: gather env1, scalars1, final MLP, output mix (fp32 out).
// ---------------------------------------------------------------------------
__global__ __launch_bounds__(256) void phaseC(
    const int* __restrict__ eidx, const float* __restrict__ env1,
    const unsigned short* __restrict__ Whf0, const unsigned short* __restrict__ Wlf0,
    const unsigned short* __restrict__ Whf1, const unsigned short* __restrict__ Wlf1,
    const unsigned short* __restrict__ latbuf, const unsigned short* __restrict__ featbuf,
    float* __restrict__ outp, int E)
{
    __shared__ __align__(16) char sm[60672];
    unsigned short (*X7)[200] = (unsigned short (*)[200])sm;              // lat2|scal1
    unsigned short (*Ft)[136] = (unsigned short (*)[136])(sm + 25600);    // feat2
    unsigned short (*Gt)[136] = (unsigned short (*)[136])(sm + 43008);    // env1 gather
    unsigned short (*Hs)[136] = (unsigned short (*)[136])(sm + 43008);    // overlays Gt (dead)
    int* snode                = (int*)(sm + 60416);

    const int tid = threadIdx.x;
    const int lane = tid & 63;
    const int w = tid >> 6;
    const int e0 = blockIdx.x * 64;
    const int E1 = E - 1;
    const int r = lane & 15, q = lane >> 4;

    if (tid < 64) snode[tid] = eidx[min(e0 + tid, E1)];
    __syncthreads();

    for (int i = tid; i < 64 * 64; i += 256) {
        int t = i >> 6, dc = i & 63;
        int e = min(e0 + t, E1);
        ((unsigned int*)&X7[t][0])[dc] = ((const unsigned int*)(latbuf + (size_t)e * 128))[dc];
        ((unsigned int*)&Ft[t][0])[dc] = ((const unsigned int*)(featbuf + (size_t)e * 128))[dc];
    }
    for (int i = tid; i < 64 * 128; i += 256) {
        int t = i >> 7, c = i & 127;
        Gt[t][c] = f2bf(env1[(size_t)snode[t] * 128 + c] * SEG_NORM);
    }
    __syncthreads();

    for (int i = tid; i < 64 * 32; i += 256) {
        int t = i >> 5, mm = i & 31;
        float f0 = bf2f(Ft[t][4 * mm]),     g0 = bf2f(Gt[t][4 * mm]);
        float f1 = bf2f(Ft[t][4 * mm + 1]), g1 = bf2f(Gt[t][4 * mm + 1]);
        float f2 = bf2f(Ft[t][4 * mm + 2]), g2 = bf2f(Gt[t][4 * mm + 2]);
        float f3 = bf2f(Ft[t][4 * mm + 3]), g3 = bf2f(Gt[t][4 * mm + 3]);
        X7[t][128 + mm] = f2bf(f0 * g0);
        X7[t][160 + mm] = f2bf((f1 * g1 + f2 * g2 + f3 * g3) * INV_SQRT3);
    }
    __syncthreads();

    const f4_t z = {0.f, 0.f, 0.f, 0.f};
    f4_t acc[8];
#pragma unroll
    for (int n = 0; n < 8; ++n) acc[n] = z;
    gemm_strip<6, 8>(&X7[w * 16][0], 200, Whf0, Wlf0, 192, lane, acc);
#pragma unroll
    for (int n = 0; n < 8; ++n)
#pragma unroll
        for (int jj = 0; jj < 4; ++jj)
            Hs[w * 16 + q * 4 + jj][n * 16 + r] = f2bf(silu_f(acc[n][jj] * RSQRT192));
    __syncthreads();

#pragma unroll
    for (int n = 0; n < 8; ++n) acc[n] = z;
    gemm_strip<4, 8>(&Hs[w * 16][0], 136, Whf1, Wlf1, 128, lane, acc);
#pragma unroll
    for (int n = 0; n < 8; ++n)
#pragma unroll
        for (int jj = 0; jj < 4; ++jj) {
            int row = w * 16 + q * 4 + jj, cc = n * 16 + r;
            int e = e0 + row;
            if (e < E)
                outp[(size_t)e * 128 + cc] =
                    SQ23 * bf2f(X7[row][cc]) + SQ13 * (acc[n][jj] * RSQRT128);
        }
}

extern "C" void kernel_launch(void* const* d_in, const int* in_sizes, int n_in,
                              void* d_out, int out_size, void* d_ws, size_t ws_size,
                              hipStream_t stream)
{
    const int E  = in_sizes[0] / 2;
    const int NN = 12500;

    const int*   eidx    = (const int*)d_in[0];
    const float* attr    = (const float*)d_in[1];
    const float* inv     = (const float*)d_in[2];
    const float* W2b0    = (const float*)d_in[3];
    const float* W2b1    = (const float*)d_in[4];
    const float* Wenv0   = (const float*)d_in[5];
    const float* Wlat1_0 = (const float*)d_in[6];
    const float* Wlat1_1 = (const float*)d_in[7];
    const float* Wenv1   = (const float*)d_in[8];
    const float* Ws0     = (const float*)d_in[9];
    const float* Wv0     = (const float*)d_in[10];
    const float* Wfin0   = (const float*)d_in[11];
    const float* Wfin1   = (const float*)d_in[12];
    float* outp = (float*)d_out;

    // ws: lat bf16 | feat bf16 | env0 f32 | env1 f32 | weight area (bf16 hi/lo)
    unsigned short* latbuf  = (unsigned short*)d_ws;
    unsigned short* featbuf = latbuf + (size_t)E * 128;
    float* env0 = (float*)(featbuf + (size_t)E * 128);
    float* env1 = env0 + (size_t)NN * 128;
    unsigned short* p = (unsigned short*)(env1 + (size_t)NN * 128);
    auto carve = [&](int elems) { unsigned short* q0 = p; p += elems; return q0; };
    unsigned short *Wh2b0 = carve(128 * 32),  *Wl2b0 = carve(128 * 32);
    unsigned short *Wh2b1 = carve(128 * 128), *Wl2b1 = carve(128 * 128);
    unsigned short *Whe0  = carve(128 * 128), *Wle0  = carve(128 * 128);
    unsigned short *Whl10 = carve(128 * 192), *Wll10 = carve(128 * 192);
    unsigned short *Whl11 = carve(128 * 128), *Wll11 = carve(128 * 128);
    unsigned short *Whe1  = carve(64 * 128),  *Wle1  = carve(64 * 128);
    unsigned short *Whs0  = carve(32 * 64),   *Wls0  = carve(32 * 64);
    unsigned short *Whv0  = carve(32 * 64),   *Wlv0  = carve(32 * 64);
    unsigned short *Whf0  = carve(128 * 192), *Wlf0  = carve(128 * 192);
    unsigned short *Whf1  = carve(128 * 128), *Wlf1  = carve(128 * 128);

    hipMemsetAsync(env0, 0, (size_t)NN * 128 * 2 * sizeof(float), stream);

    auto g = [](int n) { return (n + 255) / 256; };
    prep_w<<<g(128 * 32), 256, 0, stream>>>(W2b0, Wh2b0, Wl2b0, 8, 128, 32, 0);
    prep_w<<<g(128 * 128), 256, 0, stream>>>(W2b1, Wh2b1, Wl2b1, 128, 128, 128, 0);
    prep_w<<<g(128 * 128), 256, 0, stream>>>(Wenv0, Whe0, Wle0, 128, 128, 128, 0);
    prep_w<<<g(128 * 192), 256, 0, stream>>>(Wlat1_0, Whl10, Wll10, 192, 128, 192, 1);
    prep_w<<<g(128 * 128), 256, 0, stream>>>(Wlat1_1, Whl11, Wll11, 128, 128, 128, 0);
    prep_w<<<g(64 * 128), 256, 0, stream>>>(Wenv1, Whe1, Wle1, 128, 64, 128, 0);
    prep_w<<<g(32 * 64), 256, 0, stream>>>(Ws0, Whs0, Wls0, 64, 32, 64, 0);
    prep_w<<<g(32 * 64), 256, 0, stream>>>(Wv0, Whv0, Wlv0, 64, 32, 64, 0);
    prep_w<<<g(128 * 192), 256, 0, stream>>>(Wfin0, Whf0, Wlf0, 192, 128, 192, 1);
    prep_w<<<g(128 * 128), 256, 0, stream>>>(Wfin1, Whf1, Wlf1, 128, 128, 128, 0);

    const int nb = (E + 63) / 64;
    phaseA<<<nb, 256, 0, stream>>>(eidx, attr, inv, Wh2b0, Wl2b0, Wh2b1, Wl2b1,
                                   Whe0, Wle0, latbuf, featbuf, env0, E);
    phaseB<<<nb, 256, 0, stream>>>(eidx, attr, env0, Whs0, Wls0, Whv0, Wlv0,
                                   Whl10, Wll10, Whl11, Wll11, Whe1, Wle1,
                                   latbuf, featbuf, env1, E);
    phaseC<<<nb, 256, 0, stream>>>(eidx, env1, Whf0, Wlf0, Whf1, Wlf1,
                                   latbuf, featbuf, outp, E);
}

// Round 5
// 1005.774 us; speedup vs baseline: 3.6890x; 1.2401x over previous
//
#include <hip/hip_runtime.h>

typedef __attribute__((ext_vector_type(8))) short bf8_t;   // 8 x bf16 (4 VGPRs)
typedef __attribute__((ext_vector_type(4))) float f4_t;    // 4 x fp32 acc
typedef unsigned short u16;

#define MFMA16 __builtin_amdgcn_mfma_f32_16x16x32_bf16

#define RSQRT8    0.35355339059327373f
#define RSQRT128  0.08838834764831845f
#define RSQRT192  0.07216878364870323f
#define RSQRT64   0.125f
#define INV_SQRT3 0.57735026918962576f
#define SEG_NORM  0.25f       /* 1/sqrt(16) */
#define C_HALF    0.70710678118654752f
#define SQ23      0.81649658092772603f
#define SQ13      0.57735026918962576f

__device__ __forceinline__ float bf2f(u16 b) {
    return __uint_as_float(((unsigned int)b) << 16);
}
__device__ __forceinline__ u16 f2bf(float f) {
    unsigned int u = __float_as_uint(f);
    u += 0x7FFFu + ((u >> 16) & 1u);           // round-to-nearest-even
    return (u16)(u >> 16);
}
__device__ __forceinline__ float silu_f(float x) { return x / (1.0f + __expf(-x)); }

// One wave computes a 16-row strip x NTILES*16-col block of C = A @ (Whi+Wlo).
// A: LDS row-major, stride `as` shorts (as*2 must be 16B multiple).
// Wh/Wl: global [N][Kp] bf16 (transposed, hi/lo split); caller pre-offsets by
// column-block rows. acc[n] covers cols n*16..n*16+15 of this wave's block.
template<int KSTEPS, int NTILES>
__device__ __forceinline__ void gemm_strip(
    const u16* A, int as,
    const u16* __restrict__ Wh, const u16* __restrict__ Wl,
    int Kp, int lane, f4_t* acc)
{
    const int r = lane & 15, q = lane >> 4;
    const u16* arow = A + r * as + q * 8;
    const u16* wh = Wh + (size_t)r * Kp + q * 8;
    const u16* wl = Wl + (size_t)r * Kp + q * 8;
#pragma unroll 2
    for (int ks = 0; ks < KSTEPS; ++ks) {
        bf8_t a = *(const bf8_t*)(arow + ks * 32);
#pragma unroll
        for (int n = 0; n < NTILES; ++n) {
            bf8_t bh = *(const bf8_t*)(wh + n * 16 * Kp + ks * 32);
            bf8_t bl = *(const bf8_t*)(wl + n * 16 * Kp + ks * 32);
            acc[n] = MFMA16(a, bl, acc[n], 0, 0, 0);
            acc[n] = MFMA16(a, bh, acc[n], 0, 0, 0);
        }
    }
}

// ---------------------------------------------------------------------------
// Weight prep: fp32 [K][N] -> transposed bf16 hi/lo [N][Kp], zero-padded,
// optional row-permute (interleaved scalars -> concat order) for rows >= 128.
// ---------------------------------------------------------------------------
__global__ void prep_w(const float* __restrict__ src,
                       u16* __restrict__ hi, u16* __restrict__ lo,
                       int K, int N, int Kp, int perm)
{
    int i = blockIdx.x * 256 + threadIdx.x;
    if (i >= N * Kp) return;
    int n = i / Kp, k = i - n * Kp;
    int ks = k;
    if (perm && k >= 128) ks = (k < 160) ? (128 + 2 * (k - 128)) : (129 + 2 * (k - 160));
    float wv = (ks < K) ? src[(size_t)ks * N + n] : 0.f;
    u16 h = f2bf(wv);
    hi[i] = h;
    lo[i] = f2bf(wv - bf2f(h));
}

// ---------------------------------------------------------------------------
// Phase A: lat = mlp2(inv); w0 = lat@Wenv0; env_weight -> featbuf + env0 atomics
// 512 thr = 8 waves: strip s4 = w&3 (16 rows), col-half ch = w>>2 (64 cols).
// LDS 40.2 KB -> 2 blocks/CU (16 waves).
// ---------------------------------------------------------------------------
__global__ __launch_bounds__(512, 4) void phaseA(
    const int* __restrict__ eidx, const float* __restrict__ attr,
    const float* __restrict__ inv,
    const u16* __restrict__ Wh2b0, const u16* __restrict__ Wl2b0,
    const u16* __restrict__ Wh2b1, const u16* __restrict__ Wl2b1,
    const u16* __restrict__ Whenv0, const u16* __restrict__ Wlenv0,
    u16* __restrict__ latbuf, u16* __restrict__ featbuf,
    float* __restrict__ env0, int E)
{
    __shared__ __align__(16) char sm[40192];
    u16 (*Xi)[32]   = (u16 (*)[32])sm;                    // 4096
    u16 (*Hs)[136]  = (u16 (*)[136])(sm + 4096);          // 17408 (W0sb overlays)
    u16 (*Ls)[136]  = (u16 (*)[136])(sm + 21504);         // 17408
    u16 (*W0sb)[136]= (u16 (*)[136])(sm + 4096);          // overlay on Hs
    float (*sattr)[4] = (float (*)[4])(sm + 38912);       // 1024
    int* snode      = (int*)(sm + 39936);                 // 256

    const int tid = threadIdx.x;
    const int lane = tid & 63;
    const int w = tid >> 6;
    const int s4 = w & 3, ch = w >> 2;
    const int e0 = blockIdx.x * 64;
    const int E1 = E - 1;
    const int r = lane & 15, q = lane >> 4;

    for (int i = tid; i < 64 * 32; i += 512) {
        int t = i >> 5, c = i & 31;
        u16 v = 0;
        if (c < 8) v = f2bf(inv[(size_t)min(e0 + t, E1) * 8 + c]);
        Xi[t][c] = v;
    }
    if (tid < 256) { int t = tid >> 2, c = tid & 3; sattr[t][c] = attr[(size_t)min(e0 + t, E1) * 4 + c]; }
    if (tid < 64) snode[tid] = eidx[min(e0 + tid, E1)];
    __syncthreads();

    const f4_t z = {0.f, 0.f, 0.f, 0.f};
    f4_t acc[4];

    // GEMM1: inv(8->32) @ W2b0 -> silu -> Hs
#pragma unroll
    for (int n = 0; n < 4; ++n) acc[n] = z;
    gemm_strip<1, 4>(&Xi[s4 * 16][0], 32, Wh2b0 + ch * 64 * 32, Wl2b0 + ch * 64 * 32, 32, lane, acc);
#pragma unroll
    for (int n = 0; n < 4; ++n)
#pragma unroll
        for (int jj = 0; jj < 4; ++jj)
            Hs[s4 * 16 + q * 4 + jj][ch * 64 + n * 16 + r] = f2bf(silu_f(acc[n][jj] * RSQRT8));
    __syncthreads();

    // GEMM2: h(128) @ W2b1 -> lat -> Ls + latbuf
#pragma unroll
    for (int n = 0; n < 4; ++n) acc[n] = z;
    gemm_strip<4, 4>(&Hs[s4 * 16][0], 136, Wh2b1 + ch * 64 * 128, Wl2b1 + ch * 64 * 128, 128, lane, acc);
#pragma unroll
    for (int n = 0; n < 4; ++n)
#pragma unroll
        for (int jj = 0; jj < 4; ++jj) {
            int row = s4 * 16 + q * 4 + jj, cc = ch * 64 + n * 16 + r;
            u16 b = f2bf(acc[n][jj] * RSQRT128);
            Ls[row][cc] = b;
            int e = e0 + row;
            if (e < E) latbuf[(size_t)e * 128 + cc] = b;
        }
    __syncthreads();

    // GEMM3: lat(128) @ Wenv0 -> w0 (bf16, overlays dead Hs)
#pragma unroll
    for (int n = 0; n < 4; ++n) acc[n] = z;
    gemm_strip<4, 4>(&Ls[s4 * 16][0], 136, Whenv0 + ch * 64 * 128, Wlenv0 + ch * 64 * 128, 128, lane, acc);
#pragma unroll
    for (int n = 0; n < 4; ++n)
#pragma unroll
        for (int jj = 0; jj < 4; ++jj)
            W0sb[s4 * 16 + q * 4 + jj][ch * 64 + n * 16 + r] = f2bf(acc[n][jj] * RSQRT128);
    __syncthreads();

    // env_weight: 4 groups of 128 threads, each covers one edge's 128 channels
    {
        const int chn = tid & 127, grp = tid >> 7;
        const int mm = chn >> 2, jj = chn & 3;
        const int widx = (jj == 0) ? 2 * mm : 2 * mm + 1;
        if (grp < 2) {
            for (int t = grp; t < 64; t += 2) {
                int e = e0 + t;
                if (e < E) featbuf[(size_t)e * 128 + chn] = f2bf(bf2f(W0sb[t][widx]) * sattr[t][jj]);
            }
        } else {
            for (int t = grp - 2; t < 64; t += 2) {
                int e = e0 + t;
                if (e < E) atomicAdd(&env0[(size_t)snode[t] * 128 + chn],
                                     bf2f(W0sb[t][64 + widx]) * sattr[t][jj]);
            }
        }
    }
}

// ---------------------------------------------------------------------------
// Phase B: tensor products + mix -> feat2 (direct global); new_lat MLP; lat2;
// Wenv1 scatter. LDS 61.7 KB -> 2 blocks/CU (16 waves).
// ---------------------------------------------------------------------------
__global__ __launch_bounds__(512, 4) void phaseB(
    const int* __restrict__ eidx, const float* __restrict__ attr,
    const float* __restrict__ env0,
    const u16* __restrict__ Whs0, const u16* __restrict__ Wls0,
    const u16* __restrict__ Whv0, const u16* __restrict__ Wlv0,
    const u16* __restrict__ Whl10, const u16* __restrict__ Wll10,
    const u16* __restrict__ Whl11, const u16* __restrict__ Wll11,
    const u16* __restrict__ Whe1, const u16* __restrict__ Wle1,
    u16* __restrict__ latbuf, u16* __restrict__ featbuf,
    float* __restrict__ env1, int E)
{
    __shared__ __align__(16) char sm[61696];
    u16 (*X4)[200] = (u16 (*)[200])sm;                    // 25600: lat|sscal -> lat2
    u16 (*Ft)[136] = (u16 (*)[136])(sm + 25600);          // 17408: feat (Hs overlays)
    u16 (*Gt)[136] = (u16 (*)[136])(sm + 43008);          // 17408: env (W1s overlays)
    u16 (*Hs)[136] = (u16 (*)[136])(sm + 25600);          // overlay Ft (dead post-mix)
    float (*W1s)[68] = (float (*)[68])(sm + 43008);       // overlay Gt (dead post-mix)
    float (*sattr)[4] = (float (*)[4])(sm + 60416);       // 1024
    int* snode     = (int*)(sm + 61440);                  // 256

    const int tid = threadIdx.x;
    const int lane = tid & 63;
    const int w = tid >> 6;
    const int s4 = w & 3, ch = w >> 2;
    const int e0 = blockIdx.x * 64;
    const int E1 = E - 1;
    const int r = lane & 15, q = lane >> 4;

    if (tid < 256) { int t = tid >> 2, c = tid & 3; sattr[t][c] = attr[(size_t)min(e0 + t, E1) * 4 + c]; }
    if (tid < 64) snode[tid] = eidx[min(e0 + tid, E1)];
    for (int i = tid; i < 64 * 64; i += 512) {
        int t = i >> 6, dc = i & 63;
        int e = min(e0 + t, E1);
        ((unsigned int*)&X4[t][0])[dc] = ((const unsigned int*)(latbuf + (size_t)e * 128))[dc];
        ((unsigned int*)&Ft[t][0])[dc] = ((const unsigned int*)(featbuf + (size_t)e * 128))[dc];
    }
    __syncthreads();   // snode needed below
    for (int i = tid; i < 64 * 128; i += 512) {
        int t = i >> 7, c = i & 127;
        Gt[t][c] = f2bf(env0[(size_t)snode[t] * 128 + c] * SEG_NORM);
    }
    __syncthreads();

    // sscal (concat order; W rows 128.. pre-permuted): X4[128+mm]=ss, [160+mm]=vv
    for (int i = tid; i < 64 * 32; i += 512) {
        int t = i >> 5, mm = i & 31;
        float f0 = bf2f(Ft[t][4 * mm]),     g0 = bf2f(Gt[t][4 * mm]);
        float f1 = bf2f(Ft[t][4 * mm + 1]), g1 = bf2f(Gt[t][4 * mm + 1]);
        float f2 = bf2f(Ft[t][4 * mm + 2]), g2 = bf2f(Gt[t][4 * mm + 2]);
        float f3 = bf2f(Ft[t][4 * mm + 3]), g3 = bf2f(Gt[t][4 * mm + 3]);
        X4[t][128 + mm] = f2bf(f0 * g0);
        X4[t][160 + mm] = f2bf((f1 * g1 + f2 * g2 + f3 * g3) * INV_SQRT3);
    }
    __syncthreads();

    const f4_t z = {0.f, 0.f, 0.f, 0.f};

    // ---- mix: S-path GEMM + 3 v-dim GEMMs with on-the-fly A-frags ----
    f4_t aS = z, aV[3] = {z, z, z};
    gemm_strip<2, 1>(&X4[s4 * 16][128], 200, Whs0 + ch * 16 * 64, Wls0 + ch * 16 * 64, 64, lane, &aS);
    {
        const int arow = s4 * 16 + r;
        const u16* wv_h = Whv0 + (size_t)(ch * 16 + r) * 64 + q * 8;
        const u16* wv_l = Wlv0 + (size_t)(ch * 16 + r) * 64 + q * 8;
        bf8_t b0h = *(const bf8_t*)(wv_h);
        bf8_t b0l = *(const bf8_t*)(wv_l);
        bf8_t b1h = *(const bf8_t*)(wv_h + 32);
        bf8_t b1l = *(const bf8_t*)(wv_l + 32);
        float f0v[8], g0v[8];
#pragma unroll
        for (int jj = 0; jj < 8; ++jj) {
            int c = q * 8 + jj;
            f0v[jj] = bf2f(Ft[arow][4 * c]);
            g0v[jj] = bf2f(Gt[arow][4 * c]);
        }
#pragma unroll
        for (int d = 1; d <= 3; ++d) {
            bf8_t a0, a1;
#pragma unroll
            for (int jj = 0; jj < 8; ++jj) {
                int c = q * 8 + jj;
                float gd = bf2f(Gt[arow][4 * c + d]);
                float fd = bf2f(Ft[arow][4 * c + d]);
                a0[jj] = (short)f2bf(f0v[jj] * gd);   // sv (k in [0,32))
                a1[jj] = (short)f2bf(fd * g0v[jj]);   // vs (k in [32,64))
            }
            aV[d - 1] = MFMA16(a0, b0l, aV[d - 1], 0, 0, 0);
            aV[d - 1] = MFMA16(a0, b0h, aV[d - 1], 0, 0, 0);
            aV[d - 1] = MFMA16(a1, b1l, aV[d - 1], 0, 0, 0);
            aV[d - 1] = MFMA16(a1, b1h, aV[d - 1], 0, 0, 0);
        }
    }
    // feat2 direct to global (L2 merges the stride-4 u16 stores)
    {
        const int m = ch * 16 + r;
#pragma unroll
        for (int reg = 0; reg < 4; ++reg) {
            int e = e0 + s4 * 16 + q * 4 + reg;
            if (e < E) {
                u16* dst = featbuf + (size_t)e * 128 + 4 * m;
                dst[0] = f2bf(aS[reg] * RSQRT64);
                dst[1] = f2bf(aV[0][reg] * (RSQRT64 * INV_SQRT3));
                dst[2] = f2bf(aV[1][reg] * (RSQRT64 * INV_SQRT3));
                dst[3] = f2bf(aV[2][reg] * (RSQRT64 * INV_SQRT3));
            }
        }
    }

    // GEMM4: [lat|sscal](192) @ Wlat1_0 (k-loop reads X4 only)
    f4_t acc[4];
#pragma unroll
    for (int n = 0; n < 4; ++n) acc[n] = z;
    gemm_strip<6, 4>(&X4[s4 * 16][0], 200, Whl10 + ch * 64 * 192, Wll10 + ch * 64 * 192, 192, lane, acc);
    __syncthreads();   // all Ft/Gt reads (mix) done -> Hs may overwrite Ft
#pragma unroll
    for (int n = 0; n < 4; ++n)
#pragma unroll
        for (int jj = 0; jj < 4; ++jj)
            Hs[s4 * 16 + q * 4 + jj][ch * 64 + n * 16 + r] = f2bf(silu_f(acc[n][jj] * RSQRT192));
    __syncthreads();

    // GEMM5: h @ Wlat1_1 -> new_lat; lat2 = C*(lat+new_lat) in place in X4
#pragma unroll
    for (int n = 0; n < 4; ++n) acc[n] = z;
    gemm_strip<4, 4>(&Hs[s4 * 16][0], 136, Whl11 + ch * 64 * 128, Wll11 + ch * 64 * 128, 128, lane, acc);
#pragma unroll
    for (int n = 0; n < 4; ++n)
#pragma unroll
        for (int jj = 0; jj < 4; ++jj) {
            int row = s4 * 16 + q * 4 + jj, cc = ch * 64 + n * 16 + r;
            float l2 = C_HALF * (bf2f(X4[row][cc]) + acc[n][jj] * RSQRT128);
            X4[row][cc] = f2bf(l2);      // cell owned by this lane-reg only
        }
    __syncthreads();

    // lat2 -> latbuf (coalesced) ; GEMM6: lat2 @ Wenv1(128x64) -> W1s (f32)
    for (int i = tid; i < 64 * 64; i += 512) {
        int t = i >> 6, dc = i & 63;
        int e = e0 + t;
        if (e < E) ((unsigned int*)(latbuf + (size_t)e * 128))[dc] = ((unsigned int*)&X4[t][0])[dc];
    }
    f4_t a6[2] = {z, z};
    gemm_strip<4, 2>(&X4[s4 * 16][0], 200, Whe1 + ch * 32 * 128, Wle1 + ch * 32 * 128, 128, lane, a6);
#pragma unroll
    for (int n = 0; n < 2; ++n)
#pragma unroll
        for (int jj = 0; jj < 4; ++jj)
            W1s[s4 * 16 + q * 4 + jj][ch * 32 + n * 16 + r] = a6[n][jj] * RSQRT128;
    __syncthreads();

    // env1 scatter: 4 groups x one edge row (128 coalesced channels)
    {
        const int chn = tid & 127, grp = tid >> 7;
        const int mm = chn >> 2, jj = chn & 3;
        const int widx = (jj == 0) ? 2 * mm : 2 * mm + 1;
        for (int t = grp; t < 64; t += 4) {
            int e = e0 + t;
            if (e < E) atomicAdd(&env1[(size_t)snode[t] * 128 + chn],
                                 W1s[t][widx] * sattr[t][jj]);
        }
    }
}

// ---------------------------------------------------------------------------
// Phase C: gather env1, scalars1, final MLP, output mix (fp32 out).
// LDS 60.7 KB -> 2 blocks/CU.
// ---------------------------------------------------------------------------
__global__ __launch_bounds__(512, 4) void phaseC(
    const int* __restrict__ eidx, const float* __restrict__ env1,
    const u16* __restrict__ Whf0, const u16* __restrict__ Wlf0,
    const u16* __restrict__ Whf1, const u16* __restrict__ Wlf1,
    const u16* __restrict__ latbuf, const u16* __restrict__ featbuf,
    float* __restrict__ outp, int E)
{
    __shared__ __align__(16) char sm[60672];
    u16 (*X7)[200] = (u16 (*)[200])sm;                    // lat2|scal1
    u16 (*Ft)[136] = (u16 (*)[136])(sm + 25600);          // feat2
    u16 (*Gt)[136] = (u16 (*)[136])(sm + 43008);          // env1 (Hs overlays)
    u16 (*Hs)[136] = (u16 (*)[136])(sm + 43008);
    int* snode     = (int*)(sm + 60416);

    const int tid = threadIdx.x;
    const int lane = tid & 63;
    const int w = tid >> 6;
    const int s4 = w & 3, ch = w >> 2;
    const int e0 = blockIdx.x * 64;
    const int E1 = E - 1;
    const int r = lane & 15, q = lane >> 4;

    if (tid < 64) snode[tid] = eidx[min(e0 + tid, E1)];
    for (int i = tid; i < 64 * 64; i += 512) {
        int t = i >> 6, dc = i & 63;
        int e = min(e0 + t, E1);
        ((unsigned int*)&X7[t][0])[dc] = ((const unsigned int*)(latbuf + (size_t)e * 128))[dc];
        ((unsigned int*)&Ft[t][0])[dc] = ((const unsigned int*)(featbuf + (size_t)e * 128))[dc];
    }
    __syncthreads();
    for (int i = tid; i < 64 * 128; i += 512) {
        int t = i >> 7, c = i & 127;
        Gt[t][c] = f2bf(env1[(size_t)snode[t] * 128 + c] * SEG_NORM);
    }
    __syncthreads();

    for (int i = tid; i < 64 * 32; i += 512) {
        int t = i >> 5, mm = i & 31;
        float f0 = bf2f(Ft[t][4 * mm]),     g0 = bf2f(Gt[t][4 * mm]);
        float f1 = bf2f(Ft[t][4 * mm + 1]), g1 = bf2f(Gt[t][4 * mm + 1]);
        float f2 = bf2f(Ft[t][4 * mm + 2]), g2 = bf2f(Gt[t][4 * mm + 2]);
        float f3 = bf2f(Ft[t][4 * mm + 3]), g3 = bf2f(Gt[t][4 * mm + 3]);
        X7[t][128 + mm] = f2bf(f0 * g0);
        X7[t][160 + mm] = f2bf((f1 * g1 + f2 * g2 + f3 * g3) * INV_SQRT3);
    }
    __syncthreads();

    const f4_t z = {0.f, 0.f, 0.f, 0.f};
    f4_t acc[4];
#pragma unroll
    for (int n = 0; n < 4; ++n) acc[n] = z;
    gemm_strip<6, 4>(&X7[s4 * 16][0], 200, Whf0 + ch * 64 * 192, Wlf0 + ch * 64 * 192, 192, lane, acc);
    __syncthreads();   // all Gt reads done -> Hs may overwrite
#pragma unroll
    for (int n = 0; n < 4; ++n)
#pragma unroll
        for (int jj = 0; jj < 4; ++jj)
            Hs[s4 * 16 + q * 4 + jj][ch * 64 + n * 16 + r] = f2bf(silu_f(acc[n][jj] * RSQRT192));
    __syncthreads();

#pragma unroll
    for (int n = 0; n < 4; ++n) acc[n] = z;
    gemm_strip<4, 4>(&Hs[s4 * 16][0], 136, Whf1 + ch * 64 * 128, Wlf1 + ch * 64 * 128, 128, lane, acc);
#pragma unroll
    for (int n = 0; n < 4; ++n)
#pragma unroll
        for (int jj = 0; jj < 4; ++jj) {
            int row = s4 * 16 + q * 4 + jj, cc = ch * 64 + n * 16 + r;
            int e = e0 + row;
            if (e < E)
                outp[(size_t)e * 128 + cc] =
                    SQ23 * bf2f(X7[row][cc]) + SQ13 * (acc[n][jj] * RSQRT128);
        }
}

extern "C" void kernel_launch(void* const* d_in, const int* in_sizes, int n_in,
                              void* d_out, int out_size, void* d_ws, size_t ws_size,
                              hipStream_t stream)
{
    const int E  = in_sizes[0] / 2;
    const int NN = 12500;

    const int*   eidx    = (const int*)d_in[0];
    const float* attr    = (const float*)d_in[1];
    const float* inv     = (const float*)d_in[2];
    const float* W2b0    = (const float*)d_in[3];
    const float* W2b1    = (const float*)d_in[4];
    const float* Wenv0   = (const float*)d_in[5];
    const float* Wlat1_0 = (const float*)d_in[6];
    const float* Wlat1_1 = (const float*)d_in[7];
    const float* Wenv1   = (const float*)d_in[8];
    const float* Ws0     = (const float*)d_in[9];
    const float* Wv0     = (const float*)d_in[10];
    const float* Wfin0   = (const float*)d_in[11];
    const float* Wfin1   = (const float*)d_in[12];
    float* outp = (float*)d_out;

    // ws: lat bf16 | feat bf16 | env0 f32 | env1 f32 | weights (bf16 hi/lo)
    u16* latbuf  = (u16*)d_ws;
    u16* featbuf = latbuf + (size_t)E * 128;
    float* env0 = (float*)(featbuf + (size_t)E * 128);
    float* env1 = env0 + (size_t)NN * 128;
    u16* p = (u16*)(env1 + (size_t)NN * 128);
    auto carve = [&](int elems) { u16* q0 = p; p += elems; return q0; };
    u16 *Wh2b0 = carve(128 * 32),  *Wl2b0 = carve(128 * 32);
    u16 *Wh2b1 = carve(128 * 128), *Wl2b1 = carve(128 * 128);
    u16 *Whe0  = carve(128 * 128), *Wle0  = carve(128 * 128);
    u16 *Whl10 = carve(128 * 192), *Wll10 = carve(128 * 192);
    u16 *Whl11 = carve(128 * 128), *Wll11 = carve(128 * 128);
    u16 *Whe1  = carve(64 * 128),  *Wle1  = carve(64 * 128);
    u16 *Whs0  = carve(32 * 64),   *Wls0  = carve(32 * 64);
    u16 *Whv0  = carve(32 * 64),   *Wlv0  = carve(32 * 64);
    u16 *Whf0  = carve(128 * 192), *Wlf0  = carve(128 * 192);
    u16 *Whf1  = carve(128 * 128), *Wlf1  = carve(128 * 128);

    hipMemsetAsync(env0, 0, (size_t)NN * 128 * 2 * sizeof(float), stream);

    auto g = [](int n) { return (n + 255) / 256; };
    prep_w<<<g(128 * 32), 256, 0, stream>>>(W2b0, Wh2b0, Wl2b0, 8, 128, 32, 0);
    prep_w<<<g(128 * 128), 256, 0, stream>>>(W2b1, Wh2b1, Wl2b1, 128, 128, 128, 0);
    prep_w<<<g(128 * 128), 256, 0, stream>>>(Wenv0, Whe0, Wle0, 128, 128, 128, 0);
    prep_w<<<g(128 * 192), 256, 0, stream>>>(Wlat1_0, Whl10, Wll10, 192, 128, 192, 1);
    prep_w<<<g(128 * 128), 256, 0, stream>>>(Wlat1_1, Whl11, Wll11, 128, 128, 128, 0);
    prep_w<<<g(64 * 128), 256, 0, stream>>>(Wenv1, Whe1, Wle1, 128, 64, 128, 0);
    prep_w<<<g(32 * 64), 256, 0, stream>>>(Ws0, Whs0, Wls0, 64, 32, 64, 0);
    prep_w<<<g(32 * 64), 256, 0, stream>>>(Wv0, Whv0, Wlv0, 64, 32, 64, 0);
    prep_w<<<g(128 * 192), 256, 0, stream>>>(Wfin0, Whf0, Wlf0, 192, 128, 192, 1);
    prep_w<<<g(128 * 128), 256, 0, stream>>>(Wfin1, Whf1, Wlf1, 128, 128, 128, 0);

    const int nb = (E + 63) / 64;
    phaseA<<<nb, 512, 0, stream>>>(eidx, attr, inv, Wh2b0, Wl2b0, Wh2b1, Wl2b1,
                                   Whe0, Wle0, latbuf, featbuf, env0, E);
    phaseB<<<nb, 512, 0, stream>>>(eidx, attr, env0, Whs0, Wls0, Whv0, Wlv0,
                                   Whl10, Wll10, Whl11, Wll11, Whe1, Wle1,
                                   latbuf, featbuf, env1, E);
    phaseC<<<nb, 512, 0, stream>>>(eidx, env1, Whf0, Wlf0, Whf1, Wlf1,
                                   latbuf, featbuf, outp, E);
}

// Round 6
// 1003.493 us; speedup vs baseline: 3.6974x; 1.0023x over previous
//
#include <hip/hip_runtime.h>

typedef __attribute__((ext_vector_type(8))) short bf8_t;   // 8 x bf16 (4 VGPRs)
typedef __attribute__((ext_vector_type(4))) float f4_t;    // 4 x fp32 acc
typedef unsigned short u16;

#define MFMA16 __builtin_amdgcn_mfma_f32_16x16x32_bf16

#define RSQRT8    0.35355339059327373f
#define RSQRT128  0.08838834764831845f
#define RSQRT192  0.07216878364870323f
#define RSQRT64   0.125f
#define INV_SQRT3 0.57735026918962576f
#define SEG_NORM  0.25f       /* 1/sqrt(16) */
#define C_HALF    0.70710678118654752f
#define SQ23      0.81649658092772603f
#define SQ13      0.57735026918962576f

__device__ __forceinline__ float bf2f(u16 b) {
    return __uint_as_float(((unsigned int)b) << 16);
}
__device__ __forceinline__ u16 f2bf(float f) {
    unsigned int u = __float_as_uint(f);
    u += 0x7FFFu + ((u >> 16) & 1u);           // round-to-nearest-even
    return (u16)(u >> 16);
}
__device__ __forceinline__ float silu_f(float x) { return x / (1.0f + __expf(-x)); }

// One wave computes a 16-row strip x NTILES*16-col block of C = A @ (Whi+Wlo).
template<int KSTEPS, int NTILES>
__device__ __forceinline__ void gemm_strip(
    const u16* A, int as,
    const u16* __restrict__ Wh, const u16* __restrict__ Wl,
    int Kp, int lane, f4_t* acc)
{
    const int r = lane & 15, q = lane >> 4;
    const u16* arow = A + r * as + q * 8;
    const u16* wh = Wh + (size_t)r * Kp + q * 8;
    const u16* wl = Wl + (size_t)r * Kp + q * 8;
#pragma unroll 2
    for (int ks = 0; ks < KSTEPS; ++ks) {
        bf8_t a = *(const bf8_t*)(arow + ks * 32);
#pragma unroll
        for (int n = 0; n < NTILES; ++n) {
            bf8_t bh = *(const bf8_t*)(wh + n * 16 * Kp + ks * 32);
            bf8_t bl = *(const bf8_t*)(wl + n * 16 * Kp + ks * 32);
            acc[n] = MFMA16(a, bl, acc[n], 0, 0, 0);
            acc[n] = MFMA16(a, bh, acc[n], 0, 0, 0);
        }
    }
}

// env_weight epilogue store: weight col w (0..63 within half) -> channels.
__device__ __forceinline__ void env_store(u16* dst, int w, float val, float4 av)
{
    int m = w >> 1;
    if ((w & 1) == 0) {
        dst[4 * m] = f2bf(val * av.x);
    } else {
        dst[4 * m + 1] = f2bf(val * av.y);
        dst[4 * m + 2] = f2bf(val * av.z);
        dst[4 * m + 3] = f2bf(val * av.w);
    }
}

// ---------------------------------------------------------------------------
// Weight prep (single kernel, 10 regions): fp32 [K][N] -> bf16 hi/lo [N][Kp].
// ---------------------------------------------------------------------------
struct PD { const float* src; u16* hi; u16* lo; int K, N, Kp, perm, off, cnt; };
struct PDs { PD d[10]; };

__global__ __launch_bounds__(256) void prep_all(PDs P, int total)
{
    int i = blockIdx.x * 256 + threadIdx.x;
    if (i >= total) return;
#pragma unroll
    for (int rg = 0; rg < 10; ++rg) {
        if (i >= P.d[rg].off && i < P.d[rg].off + P.d[rg].cnt) {
            int li = i - P.d[rg].off;
            int n = li / P.d[rg].Kp, k = li - n * P.d[rg].Kp;
            int ks = k;
            if (P.d[rg].perm && k >= 128)
                ks = (k < 160) ? (128 + 2 * (k - 128)) : (129 + 2 * (k - 160));
            float wv = (ks < P.d[rg].K) ? P.d[rg].src[(size_t)ks * P.d[rg].N + n] : 0.f;
            u16 h = f2bf(wv);
            P.d[rg].hi[li] = h;
            P.d[rg].lo[li] = f2bf(wv - bf2f(h));
        }
    }
}

// ---------------------------------------------------------------------------
// Counting sort of edges by center node (replaces all fp32 atomics).
// ---------------------------------------------------------------------------
__global__ __launch_bounds__(256) void hist_k(const int* __restrict__ eidx,
                                              int* __restrict__ cnt, int E)
{
    int i = blockIdx.x * 256 + threadIdx.x;
    if (i < E) atomicAdd(&cnt[eidx[i]], 1);
}

__global__ __launch_bounds__(1024) void scan_k(const int* __restrict__ cnt,
                                               int* __restrict__ base,
                                               int* __restrict__ cursor, int NN)
{
    __shared__ int part[1024];
    const int t = threadIdx.x;
    const int CHK = (NN + 1023) >> 10;
    int s = 0;
    for (int k = 0; k < CHK; ++k) { int idx = t * CHK + k; if (idx < NN) s += cnt[idx]; }
    part[t] = s;
    __syncthreads();
    for (int off = 1; off < 1024; off <<= 1) {
        int v = (t >= off) ? part[t - off] : 0;
        __syncthreads();
        part[t] += v;
        __syncthreads();
    }
    if (t == 0) base[NN] = part[1023];
    int run = (t == 0) ? 0 : part[t - 1];
    for (int k = 0; k < CHK; ++k) {
        int idx = t * CHK + k;
        if (idx < NN) { base[idx] = run; cursor[idx] = run; run += cnt[idx]; }
    }
}

__global__ __launch_bounds__(256) void scatter_k(const int* __restrict__ eidx,
                                                 int* __restrict__ cursor,
                                                 int* __restrict__ sorted, int E)
{
    int i = blockIdx.x * 256 + threadIdx.x;
    if (i < E) {
        int p = atomicAdd(&cursor[eidx[i]], 1);
        sorted[p] = i;
    }
}

// ---------------------------------------------------------------------------
// Segment reduction: env[node] = (sum over node's edges of env_e) * SEG_NORM.
// 2 nodes per 256-thr block; fp32 register accumulate; bf16 out (pre-normed).
// ---------------------------------------------------------------------------
__global__ __launch_bounds__(256) void reduce_env(
    const int* __restrict__ base, const int* __restrict__ sorted,
    const u16* __restrict__ enve, u16* __restrict__ env, int NN)
{
    const int half = __builtin_amdgcn_readfirstlane(threadIdx.x >> 7);
    const int node = blockIdx.x * 2 + half;
    const int ch = threadIdx.x & 127;
    if (node >= NN) return;
    const int b = base[node], en = base[node + 1];
    float acc = 0.f;
    int i = b;
    for (; i + 3 < en; i += 4) {
        int s0 = sorted[i], s1 = sorted[i + 1], s2 = sorted[i + 2], s3 = sorted[i + 3];
        float v0 = bf2f(enve[(size_t)s0 * 128 + ch]);
        float v1 = bf2f(enve[(size_t)s1 * 128 + ch]);
        float v2 = bf2f(enve[(size_t)s2 * 128 + ch]);
        float v3 = bf2f(enve[(size_t)s3 * 128 + ch]);
        acc += (v0 + v1) + (v2 + v3);
    }
    for (; i < en; ++i) acc += bf2f(enve[(size_t)sorted[i] * 128 + ch]);
    env[(size_t)node * 128 + ch] = f2bf(acc * SEG_NORM);
}

// ---------------------------------------------------------------------------
// Phase A: lat = mlp2(inv); w0 = lat@Wenv0; env_weight -> featbuf + env_e rows.
// 512 thr = 8 waves: strip s4 = w&3 (16 rows), col-half ch = w>>2 (64 cols).
// ---------------------------------------------------------------------------
__global__ __launch_bounds__(512, 4) void phaseA(
    const float* __restrict__ attr, const float* __restrict__ inv,
    const u16* __restrict__ Wh2b0, const u16* __restrict__ Wl2b0,
    const u16* __restrict__ Wh2b1, const u16* __restrict__ Wl2b1,
    const u16* __restrict__ Whenv0, const u16* __restrict__ Wlenv0,
    u16* __restrict__ latbuf, u16* __restrict__ featbuf,
    u16* __restrict__ enve, int E)
{
    __shared__ __align__(16) char sm[39936];
    u16 (*Xi)[32]  = (u16 (*)[32])sm;                     // 4096
    u16 (*Hs)[136] = (u16 (*)[136])(sm + 4096);           // 17408
    u16 (*Ls)[136] = (u16 (*)[136])(sm + 21504);          // 17408
    float (*sattr)[4] = (float (*)[4])(sm + 38912);       // 1024

    const int tid = threadIdx.x;
    const int lane = tid & 63;
    const int w = tid >> 6;
    const int s4 = w & 3, ch = w >> 2;
    const int e0 = blockIdx.x * 64;
    const int E1 = E - 1;
    const int r = lane & 15, q = lane >> 4;

    for (int i = tid; i < 64 * 32; i += 512) {
        int t = i >> 5, c = i & 31;
        u16 v = 0;
        if (c < 8) v = f2bf(inv[(size_t)min(e0 + t, E1) * 8 + c]);
        Xi[t][c] = v;
    }
    if (tid < 256) { int t = tid >> 2, c = tid & 3; sattr[t][c] = attr[(size_t)min(e0 + t, E1) * 4 + c]; }
    __syncthreads();

    const f4_t z = {0.f, 0.f, 0.f, 0.f};
    f4_t acc[4];

    // GEMM1: inv(8->32) @ W2b0 -> silu -> Hs
#pragma unroll
    for (int n = 0; n < 4; ++n) acc[n] = z;
    gemm_strip<1, 4>(&Xi[s4 * 16][0], 32, Wh2b0 + ch * 64 * 32, Wl2b0 + ch * 64 * 32, 32, lane, acc);
#pragma unroll
    for (int n = 0; n < 4; ++n)
#pragma unroll
        for (int jj = 0; jj < 4; ++jj)
            Hs[s4 * 16 + q * 4 + jj][ch * 64 + n * 16 + r] = f2bf(silu_f(acc[n][jj] * RSQRT8));
    __syncthreads();

    // GEMM2: h(128) @ W2b1 -> lat -> Ls + latbuf
#pragma unroll
    for (int n = 0; n < 4; ++n) acc[n] = z;
    gemm_strip<4, 4>(&Hs[s4 * 16][0], 136, Wh2b1 + ch * 64 * 128, Wl2b1 + ch * 64 * 128, 128, lane, acc);
#pragma unroll
    for (int n = 0; n < 4; ++n)
#pragma unroll
        for (int jj = 0; jj < 4; ++jj) {
            int row = s4 * 16 + q * 4 + jj, cc = ch * 64 + n * 16 + r;
            u16 b = f2bf(acc[n][jj] * RSQRT128);
            Ls[row][cc] = b;
            int e = e0 + row;
            if (e < E) latbuf[(size_t)e * 128 + cc] = b;
        }
    __syncthreads();

    // GEMM3: lat(128) @ Wenv0 -> w0; direct env_weight stores from accumulators.
    // ch==0 waves hold cols 0..63 (features); ch==1 waves cols 64..127 (env_e).
#pragma unroll
    for (int n = 0; n < 4; ++n) acc[n] = z;
    gemm_strip<4, 4>(&Ls[s4 * 16][0], 136, Whenv0 + ch * 64 * 128, Wlenv0 + ch * 64 * 128, 128, lane, acc);
#pragma unroll
    for (int jj = 0; jj < 4; ++jj) {
        int row = s4 * 16 + q * 4 + jj;
        int e = e0 + row;
        if (e >= E) continue;
        float4 av = *(const float4*)&sattr[row][0];
        u16* dst = ((ch == 0) ? featbuf : enve) + (size_t)e * 128;
#pragma unroll
        for (int n = 0; n < 4; ++n)
            env_store(dst, n * 16 + r, acc[n][jj] * RSQRT128, av);
    }
}

// ---------------------------------------------------------------------------
// Phase B: tensor products + mix -> feat2; new_lat MLP; lat2; w1 -> env_e rows.
// ---------------------------------------------------------------------------
__global__ __launch_bounds__(512, 4) void phaseB(
    const int* __restrict__ eidx, const float* __restrict__ attr,
    const u16* __restrict__ env0b,
    const u16* __restrict__ Whs0, const u16* __restrict__ Wls0,
    const u16* __restrict__ Whv0, const u16* __restrict__ Wlv0,
    const u16* __restrict__ Whl10, const u16* __restrict__ Wll10,
    const u16* __restrict__ Whl11, const u16* __restrict__ Wll11,
    const u16* __restrict__ Whe1, const u16* __restrict__ Wle1,
    u16* __restrict__ latbuf, u16* __restrict__ featbuf,
    u16* __restrict__ enve, int E)
{
    __shared__ __align__(16) char sm[61696];
    u16 (*X4)[200] = (u16 (*)[200])sm;                    // 25600: lat|sscal -> lat2
    u16 (*Ft)[136] = (u16 (*)[136])(sm + 25600);          // 17408: feat (Hs overlays)
    u16 (*Gt)[136] = (u16 (*)[136])(sm + 43008);          // 17408: env0 gather
    u16 (*Hs)[136] = (u16 (*)[136])(sm + 25600);          // overlay Ft (dead post-mix)
    float (*sattr)[4] = (float (*)[4])(sm + 60416);       // 1024
    int* snode     = (int*)(sm + 61440);                  // 256

    const int tid = threadIdx.x;
    const int lane = tid & 63;
    const int w = tid >> 6;
    const int s4 = w & 3, ch = w >> 2;
    const int e0 = blockIdx.x * 64;
    const int E1 = E - 1;
    const int r = lane & 15, q = lane >> 4;

    if (tid < 256) { int t = tid >> 2, c = tid & 3; sattr[t][c] = attr[(size_t)min(e0 + t, E1) * 4 + c]; }
    if (tid < 64) snode[tid] = eidx[min(e0 + tid, E1)];
    for (int i = tid; i < 64 * 64; i += 512) {
        int t = i >> 6, dc = i & 63;
        int e = min(e0 + t, E1);
        ((unsigned int*)&X4[t][0])[dc] = ((const unsigned int*)(latbuf + (size_t)e * 128))[dc];
        ((unsigned int*)&Ft[t][0])[dc] = ((const unsigned int*)(featbuf + (size_t)e * 128))[dc];
    }
    __syncthreads();   // snode ready
    for (int i = tid; i < 64 * 64; i += 512) {
        int t = i >> 6, dc = i & 63;
        ((unsigned int*)&Gt[t][0])[dc] = ((const unsigned int*)(env0b + (size_t)snode[t] * 128))[dc];
    }
    __syncthreads();

    // sscal (concat order; W rows 128.. pre-permuted): X4[128+mm]=ss, [160+mm]=vv
    for (int i = tid; i < 64 * 32; i += 512) {
        int t = i >> 5, mm = i & 31;
        float f0 = bf2f(Ft[t][4 * mm]),     g0 = bf2f(Gt[t][4 * mm]);
        float f1 = bf2f(Ft[t][4 * mm + 1]), g1 = bf2f(Gt[t][4 * mm + 1]);
        float f2 = bf2f(Ft[t][4 * mm + 2]), g2 = bf2f(Gt[t][4 * mm + 2]);
        float f3 = bf2f(Ft[t][4 * mm + 3]), g3 = bf2f(Gt[t][4 * mm + 3]);
        X4[t][128 + mm] = f2bf(f0 * g0);
        X4[t][160 + mm] = f2bf((f1 * g1 + f2 * g2 + f3 * g3) * INV_SQRT3);
    }
    __syncthreads();

    const f4_t z = {0.f, 0.f, 0.f, 0.f};

    // ---- mix: S-path GEMM + 3 v-dim GEMMs with on-the-fly A-frags ----
    f4_t aS = z, aV[3] = {z, z, z};
    gemm_strip<2, 1>(&X4[s4 * 16][128], 200, Whs0 + ch * 16 * 64, Wls0 + ch * 16 * 64, 64, lane, &aS);
    {
        const int arow = s4 * 16 + r;
        const u16* wv_h = Whv0 + (size_t)(ch * 16 + r) * 64 + q * 8;
        const u16* wv_l = Wlv0 + (size_t)(ch * 16 + r) * 64 + q * 8;
        bf8_t b0h = *(const bf8_t*)(wv_h);
        bf8_t b0l = *(const bf8_t*)(wv_l);
        bf8_t b1h = *(const bf8_t*)(wv_h + 32);
        bf8_t b1l = *(const bf8_t*)(wv_l + 32);
        float f0v[8], g0v[8];
#pragma unroll
        for (int jj = 0; jj < 8; ++jj) {
            int c = q * 8 + jj;
            f0v[jj] = bf2f(Ft[arow][4 * c]);
            g0v[jj] = bf2f(Gt[arow][4 * c]);
        }
#pragma unroll
        for (int d = 1; d <= 3; ++d) {
            bf8_t a0, a1;
#pragma unroll
            for (int jj = 0; jj < 8; ++jj) {
                int c = q * 8 + jj;
                float gd = bf2f(Gt[arow][4 * c + d]);
                float fd = bf2f(Ft[arow][4 * c + d]);
                a0[jj] = (short)f2bf(f0v[jj] * gd);   // sv (k in [0,32))
                a1[jj] = (short)f2bf(fd * g0v[jj]);   // vs (k in [32,64))
            }
            aV[d - 1] = MFMA16(a0, b0l, aV[d - 1], 0, 0, 0);
            aV[d - 1] = MFMA16(a0, b0h, aV[d - 1], 0, 0, 0);
            aV[d - 1] = MFMA16(a1, b1l, aV[d - 1], 0, 0, 0);
            aV[d - 1] = MFMA16(a1, b1h, aV[d - 1], 0, 0, 0);
        }
    }
    // feat2 direct to global
    {
        const int m = ch * 16 + r;
#pragma unroll
        for (int reg = 0; reg < 4; ++reg) {
            int e = e0 + s4 * 16 + q * 4 + reg;
            if (e < E) {
                u16* dst = featbuf + (size_t)e * 128 + 4 * m;
                dst[0] = f2bf(aS[reg] * RSQRT64);
                dst[1] = f2bf(aV[0][reg] * (RSQRT64 * INV_SQRT3));
                dst[2] = f2bf(aV[1][reg] * (RSQRT64 * INV_SQRT3));
                dst[3] = f2bf(aV[2][reg] * (RSQRT64 * INV_SQRT3));
            }
        }
    }

    // GEMM4: [lat|sscal](192) @ Wlat1_0 (k-loop reads X4 only)
    f4_t acc[4];
#pragma unroll
    for (int n = 0; n < 4; ++n) acc[n] = z;
    gemm_strip<6, 4>(&X4[s4 * 16][0], 200, Whl10 + ch * 64 * 192, Wll10 + ch * 64 * 192, 192, lane, acc);
    __syncthreads();   // all Ft/Gt reads (mix) done -> Hs may overwrite Ft
#pragma unroll
    for (int n = 0; n < 4; ++n)
#pragma unroll
        for (int jj = 0; jj < 4; ++jj)
            Hs[s4 * 16 + q * 4 + jj][ch * 64 + n * 16 + r] = f2bf(silu_f(acc[n][jj] * RSQRT192));
    __syncthreads();

    // GEMM5: h @ Wlat1_1 -> new_lat; lat2 = C*(lat+new_lat) in place in X4
#pragma unroll
    for (int n = 0; n < 4; ++n) acc[n] = z;
    gemm_strip<4, 4>(&Hs[s4 * 16][0], 136, Whl11 + ch * 64 * 128, Wll11 + ch * 64 * 128, 128, lane, acc);
#pragma unroll
    for (int n = 0; n < 4; ++n)
#pragma unroll
        for (int jj = 0; jj < 4; ++jj) {
            int row = s4 * 16 + q * 4 + jj, cc = ch * 64 + n * 16 + r;
            float l2 = C_HALF * (bf2f(X4[row][cc]) + acc[n][jj] * RSQRT128);
            X4[row][cc] = f2bf(l2);      // cell owned by this lane-reg only
        }
    __syncthreads();

    // lat2 -> latbuf ; GEMM6: lat2 @ Wenv1(128x64) -> w1 -> env_e rows (direct)
    for (int i = tid; i < 64 * 64; i += 512) {
        int t = i >> 6, dc = i & 63;
        int e = e0 + t;
        if (e < E) ((unsigned int*)(latbuf + (size_t)e * 128))[dc] = ((unsigned int*)&X4[t][0])[dc];
    }
    f4_t a6[2] = {z, z};
    gemm_strip<4, 2>(&X4[s4 * 16][0], 200, Whe1 + ch * 32 * 128, Wle1 + ch * 32 * 128, 128, lane, a6);
#pragma unroll
    for (int jj = 0; jj < 4; ++jj) {
        int row = s4 * 16 + q * 4 + jj;
        int e = e0 + row;
        if (e >= E) continue;
        float4 av = *(const float4*)&sattr[row][0];
        u16* dst = enve + (size_t)e * 128;
#pragma unroll
        for (int n = 0; n < 2; ++n)
            env_store(dst, ch * 32 + n * 16 + r, a6[n][jj] * RSQRT128, av);
    }
}

// ---------------------------------------------------------------------------
// Phase C: gather env1, scalars1, final MLP, output mix (fp32 out).
// ---------------------------------------------------------------------------
__global__ __launch_bounds__(512, 4) void phaseC(
    const int* __restrict__ eidx, const u16* __restrict__ env1b,
    const u16* __restrict__ Whf0, const u16* __restrict__ Wlf0,
    const u16* __restrict__ Whf1, const u16* __restrict__ Wlf1,
    const u16* __restrict__ latbuf, const u16* __restrict__ featbuf,
    float* __restrict__ outp, int E)
{
    __shared__ __align__(16) char sm[60672];
    u16 (*X7)[200] = (u16 (*)[200])sm;                    // lat2|scal1
    u16 (*Ft)[136] = (u16 (*)[136])(sm + 25600);          // feat2
    u16 (*Gt)[136] = (u16 (*)[136])(sm + 43008);          // env1 (Hs overlays)
    u16 (*Hs)[136] = (u16 (*)[136])(sm + 43008);
    int* snode     = (int*)(sm + 60416);

    const int tid = threadIdx.x;
    const int lane = tid & 63;
    const int w = tid >> 6;
    const int s4 = w & 3, ch = w >> 2;
    const int e0 = blockIdx.x * 64;
    const int E1 = E - 1;
    const int r = lane & 15, q = lane >> 4;

    if (tid < 64) snode[tid] = eidx[min(e0 + tid, E1)];
    for (int i = tid; i < 64 * 64; i += 512) {
        int t = i >> 6, dc = i & 63;
        int e = min(e0 + t, E1);
        ((unsigned int*)&X7[t][0])[dc] = ((const unsigned int*)(latbuf + (size_t)e * 128))[dc];
        ((unsigned int*)&Ft[t][0])[dc] = ((const unsigned int*)(featbuf + (size_t)e * 128))[dc];
    }
    __syncthreads();
    for (int i = tid; i < 64 * 64; i += 512) {
        int t = i >> 6, dc = i & 63;
        ((unsigned int*)&Gt[t][0])[dc] = ((const unsigned int*)(env1b + (size_t)snode[t] * 128))[dc];
    }
    __syncthreads();

    for (int i = tid; i < 64 * 32; i += 512) {
        int t = i >> 5, mm = i & 31;
        float f0 = bf2f(Ft[t][4 * mm]),     g0 = bf2f(Gt[t][4 * mm]);
        float f1 = bf2f(Ft[t][4 * mm + 1]), g1 = bf2f(Gt[t][4 * mm + 1]);
        float f2 = bf2f(Ft[t][4 * mm + 2]), g2 = bf2f(Gt[t][4 * mm + 2]);
        float f3 = bf2f(Ft[t][4 * mm + 3]), g3 = bf2f(Gt[t][4 * mm + 3]);
        X7[t][128 + mm] = f2bf(f0 * g0);
        X7[t][160 + mm] = f2bf((f1 * g1 + f2 * g2 + f3 * g3) * INV_SQRT3);
    }
    __syncthreads();

    const f4_t z = {0.f, 0.f, 0.f, 0.f};
    f4_t acc[4];
#pragma unroll
    for (int n = 0; n < 4; ++n) acc[n] = z;
    gemm_strip<6, 4>(&X7[s4 * 16][0], 200, Whf0 + ch * 64 * 192, Wlf0 + ch * 64 * 192, 192, lane, acc);
    __syncthreads();   // all Gt reads done -> Hs may overwrite
#pragma unroll
    for (int n = 0; n < 4; ++n)
#pragma unroll
        for (int jj = 0; jj < 4; ++jj)
            Hs[s4 * 16 + q * 4 + jj][ch * 64 + n * 16 + r] = f2bf(silu_f(acc[n][jj] * RSQRT192));
    __syncthreads();

#pragma unroll
    for (int n = 0; n < 4; ++n) acc[n] = z;
    gemm_strip<4, 4>(&Hs[s4 * 16][0], 136, Whf1 + ch * 64 * 128, Wlf1 + ch * 64 * 128, 128, lane, acc);
#pragma unroll
    for (int n = 0; n < 4; ++n)
#pragma unroll
        for (int jj = 0; jj < 4; ++jj) {
            int row = s4 * 16 + q * 4 + jj, cc = ch * 64 + n * 16 + r;
            int e = e0 + row;
            if (e < E)
                outp[(size_t)e * 128 + cc] =
                    SQ23 * bf2f(X7[row][cc]) + SQ13 * (acc[n][jj] * RSQRT128);
        }
}

extern "C" void kernel_launch(void* const* d_in, const int* in_sizes, int n_in,
                              void* d_out, int out_size, void* d_ws, size_t ws_size,
                              hipStream_t stream)
{
    const int E  = in_sizes[0] / 2;
    const int NN = 12500;

    const int*   eidx    = (const int*)d_in[0];
    const float* attr    = (const float*)d_in[1];
    const float* inv     = (const float*)d_in[2];
    float* outp = (float*)d_out;

    // ws: lat bf16 | feat bf16 | env0b, env1b bf16 | weights | sort ints
    u16* latbuf  = (u16*)d_ws;
    u16* featbuf = latbuf + (size_t)E * 128;
    u16* env0b   = featbuf + (size_t)E * 128;
    u16* env1b   = env0b + (size_t)NN * 128;
    u16* p = env1b + (size_t)NN * 128;
    auto carve = [&](int elems) { u16* q0 = p; p += elems; return q0; };
    u16 *Wh2b0 = carve(128 * 32),  *Wl2b0 = carve(128 * 32);
    u16 *Wh2b1 = carve(128 * 128), *Wl2b1 = carve(128 * 128);
    u16 *Whe0  = carve(128 * 128), *Wle0  = carve(128 * 128);
    u16 *Whl10 = carve(128 * 192), *Wll10 = carve(128 * 192);
    u16 *Whl11 = carve(128 * 128), *Wll11 = carve(128 * 128);
    u16 *Whe1  = carve(64 * 128),  *Wle1  = carve(64 * 128);
    u16 *Whs0  = carve(32 * 64),   *Wls0  = carve(32 * 64);
    u16 *Whv0  = carve(32 * 64),   *Wlv0  = carve(32 * 64);
    u16 *Whf0  = carve(128 * 192), *Wlf0  = carve(128 * 192);
    u16 *Whf1  = carve(128 * 128), *Wlf1  = carve(128 * 128);
    int* ibase_p = (int*)((((size_t)(p - (u16*)0) + 1) & ~(size_t)1));  // align to 4B
    int* cnt    = (int*)d_ws + (((size_t)((u16*)ibase_p - (u16*)d_ws)) / 2);
    // simpler: recompute from p with 4-byte alignment
    {
        size_t off_bytes = (size_t)((char*)p - (char*)d_ws);
        off_bytes = (off_bytes + 3) & ~(size_t)3;
        cnt = (int*)((char*)d_ws + off_bytes);
    }
    int* base   = cnt + NN;          // NN+1 entries
    int* cursor = base + NN + 1;
    int* sorted = cursor + NN;

    // env_e scratch: reuse d_out (fully overwritten by phaseC afterwards)
    u16* enve = (u16*)d_out;

    hipMemsetAsync(cnt, 0, NN * sizeof(int), stream);

    // ---- weight prep (one kernel) ----
    PDs P;
    auto setpd = [&](int i, const float* s, u16* h, u16* l, int K, int N, int Kp, int pm, int off) {
        P.d[i] = {s, h, l, K, N, Kp, pm, off, N * Kp};
    };
    setpd(0, (const float*)d_in[3],  Wh2b0, Wl2b0,   8, 128,  32, 0, 0);
    setpd(1, (const float*)d_in[4],  Wh2b1, Wl2b1, 128, 128, 128, 0, 4096);
    setpd(2, (const float*)d_in[5],  Whe0,  Wle0,  128, 128, 128, 0, 20480);
    setpd(3, (const float*)d_in[6],  Whl10, Wll10, 192, 128, 192, 1, 36864);
    setpd(4, (const float*)d_in[7],  Whl11, Wll11, 128, 128, 128, 0, 61440);
    setpd(5, (const float*)d_in[8],  Whe1,  Wle1,  128,  64, 128, 0, 77824);
    setpd(6, (const float*)d_in[9],  Whs0,  Wls0,   64,  32,  64, 0, 86016);
    setpd(7, (const float*)d_in[10], Whv0,  Wlv0,   64,  32,  64, 0, 88064);
    setpd(8, (const float*)d_in[11], Whf0,  Wlf0,  192, 128, 192, 1, 90112);
    setpd(9, (const float*)d_in[12], Whf1,  Wlf1,  128, 128, 128, 0, 114688);
    const int total = 131072;
    prep_all<<<(total + 255) / 256, 256, 0, stream>>>(P, total);

    // ---- counting sort of edges by center node ----
    hist_k<<<(E + 255) / 256, 256, 0, stream>>>(eidx, cnt, E);
    scan_k<<<1, 1024, 0, stream>>>(cnt, base, cursor, NN);
    scatter_k<<<(E + 255) / 256, 256, 0, stream>>>(eidx, cursor, sorted, E);

    const int nb = (E + 63) / 64;
    phaseA<<<nb, 512, 0, stream>>>(attr, inv, Wh2b0, Wl2b0, Wh2b1, Wl2b1,
                                   Whe0, Wle0, latbuf, featbuf, enve, E);
    reduce_env<<<(NN + 1) / 2, 256, 0, stream>>>(base, sorted, enve, env0b, NN);
    phaseB<<<nb, 512, 0, stream>>>(eidx, attr, env0b, Whs0, Wls0, Whv0, Wlv0,
                                   Whl10, Wll10, Whl11, Wll11, Whe1, Wle1,
                                   latbuf, featbuf, enve, E);
    reduce_env<<<(NN + 1) / 2, 256, 0, stream>>>(base, sorted, enve, env1b, NN);
    phaseC<<<nb, 512, 0, stream>>>(eidx, env1b, Whf0, Wlf0, Whf1, Wlf1,
                                   latbuf, featbuf, outp, E);
}